// Round 1
// baseline (7184.071 us; speedup 1.0000x reference)
//
#include <hip/hip_runtime.h>
#include <hip/hip_bf16.h>

#define LNUM 6
#define CH 192
#define FCH 768
#define NH 2
#define DKH 96
#define WIN 4
#define BATCH 4
#define TLEN 2048
#define EPSV 1e-5f

#define NBCT (BATCH*CH*TLEN)      // 1572864 floats
#define NBFT (BATCH*FCH*TLEN)     // 6291456 floats

// ---------------- elementwise x * mask ----------------
__global__ __launch_bounds__(256) void mulmask_kernel(const float* __restrict__ X,
    const float* __restrict__ mask, float* __restrict__ Y) {
  int i = blockIdx.x * 256 + threadIdx.x;
  int b = i / (CH * TLEN);
  int t = i % TLEN;
  Y[i] = X[i] * mask[b * TLEN + t];
}

// ---------------- conv1x1: Y[b][o][t] = sum_c W[o][c] X[b][c][t] + bias[o] ----
__global__ __launch_bounds__(256) void conv1x1_kernel(
    const float* __restrict__ Wt, const float* __restrict__ bias,
    const float* __restrict__ X, float* __restrict__ Y, int O, int Cin)
{
  __shared__ __align__(16) float ws[64][33];
  __shared__ __align__(16) float xs[32][64];
  int b = blockIdx.z;
  int o0 = blockIdx.y * 64, t0 = blockIdx.x * 64;
  int tid = threadIdx.x;
  int ty4 = (tid >> 4) * 4, tx4 = (tid & 15) * 4;
  const float* Xb = X + (size_t)b * Cin * TLEN;
  float4 acc[4];
  #pragma unroll
  for (int i = 0; i < 4; ++i) { acc[i].x = 0.f; acc[i].y = 0.f; acc[i].z = 0.f; acc[i].w = 0.f; }
  for (int kc = 0; kc < Cin; kc += 32) {
    #pragma unroll
    for (int f = tid; f < 64 * 32; f += 256) {
      int r = f >> 5, c = f & 31;
      ws[r][c] = Wt[(size_t)(o0 + r) * Cin + kc + c];
    }
    #pragma unroll
    for (int f = tid; f < 512; f += 256) {
      int r = f >> 4, c4 = (f & 15) << 2;
      *(float4*)&xs[r][c4] = *(const float4*)&Xb[(size_t)(kc + r) * TLEN + t0 + c4];
    }
    __syncthreads();
    #pragma unroll 8
    for (int k = 0; k < 32; ++k) {
      float w0 = ws[ty4 + 0][k], w1 = ws[ty4 + 1][k], w2 = ws[ty4 + 2][k], w3 = ws[ty4 + 3][k];
      float4 xv = *(float4*)&xs[k][tx4];
      acc[0].x += w0 * xv.x; acc[0].y += w0 * xv.y; acc[0].z += w0 * xv.z; acc[0].w += w0 * xv.w;
      acc[1].x += w1 * xv.x; acc[1].y += w1 * xv.y; acc[1].z += w1 * xv.z; acc[1].w += w1 * xv.w;
      acc[2].x += w2 * xv.x; acc[2].y += w2 * xv.y; acc[2].z += w2 * xv.z; acc[2].w += w2 * xv.w;
      acc[3].x += w3 * xv.x; acc[3].y += w3 * xv.y; acc[3].z += w3 * xv.z; acc[3].w += w3 * xv.w;
    }
    __syncthreads();
  }
  #pragma unroll
  for (int i = 0; i < 4; ++i) {
    float bb = bias[o0 + ty4 + i];
    float4 v = acc[i];
    v.x += bb; v.y += bb; v.z += bb; v.w += bb;
    *(float4*)&Y[((size_t)b * O + o0 + ty4 + i) * TLEN + t0 + tx4] = v;
  }
}

// ---------------- conv1d kernel-size-3, pad 1 ----------------
__global__ __launch_bounds__(256) void conv1d3_kernel(
    const float* __restrict__ Wt, const float* __restrict__ bias,
    const float* __restrict__ X, float* __restrict__ Y, int O, int Cin, int relu)
{
  __shared__ __align__(16) float ws2[64][98];
  __shared__ __align__(16) float xs[32][68];
  int b = blockIdx.z;
  int o0 = blockIdx.y * 64, t0 = blockIdx.x * 64;
  int tid = threadIdx.x;
  int ty4 = (tid >> 4) * 4, tx4 = (tid & 15) * 4;
  const float* Xb = X + (size_t)b * Cin * TLEN;
  float acc[4][4] = {};
  for (int kc = 0; kc < Cin; kc += 32) {
    for (int f = tid; f < 64 * 96; f += 256) {
      int r = f / 96, cc = f - r * 96;
      ws2[r][cc] = Wt[(size_t)(o0 + r) * (Cin * 3) + kc * 3 + cc];
    }
    for (int f = tid; f < 32 * 66; f += 256) {
      int r = f / 66, c = f - r * 66;
      int t = t0 + c - 1;
      xs[r][c] = (t >= 0 && t < TLEN) ? Xb[(size_t)(kc + r) * TLEN + t] : 0.f;
    }
    __syncthreads();
    #pragma unroll 4
    for (int k = 0; k < 32; ++k) {
      float w[4][3];
      #pragma unroll
      for (int i = 0; i < 4; ++i)
        #pragma unroll
        for (int kk = 0; kk < 3; ++kk)
          w[i][kk] = ws2[ty4 + i][k * 3 + kk];
      float xr[6];
      float4 xa = *(float4*)&xs[k][tx4];
      float2 xb2 = *(float2*)&xs[k][tx4 + 4];
      xr[0] = xa.x; xr[1] = xa.y; xr[2] = xa.z; xr[3] = xa.w; xr[4] = xb2.x; xr[5] = xb2.y;
      #pragma unroll
      for (int i = 0; i < 4; ++i)
        #pragma unroll
        for (int kk = 0; kk < 3; ++kk)
          #pragma unroll
          for (int j = 0; j < 4; ++j)
            acc[i][j] += w[i][kk] * xr[j + kk];
    }
    __syncthreads();
  }
  #pragma unroll
  for (int i = 0; i < 4; ++i) {
    float bb = bias[o0 + ty4 + i];
    float4 v;
    v.x = acc[i][0] + bb; v.y = acc[i][1] + bb; v.z = acc[i][2] + bb; v.w = acc[i][3] + bb;
    if (relu) { v.x = fmaxf(v.x, 0.f); v.y = fmaxf(v.y, 0.f); v.z = fmaxf(v.z, 0.f); v.w = fmaxf(v.w, 0.f); }
    *(float4*)&Y[((size_t)b * O + o0 + ty4 + i) * TLEN + t0 + tx4] = v;
  }
}

// ---------------- fused residual-add + LayerNorm over channels ----------------
__global__ __launch_bounds__(256) void ln_kernel(
    const float* __restrict__ res, const float* __restrict__ yy,
    const float* __restrict__ g, const float* __restrict__ bt,
    float* __restrict__ out)
{
  int idx = blockIdx.x * 256 + threadIdx.x;  // covers B*T
  int b = idx / TLEN, t = idx - b * TLEN;
  const float* r = res + (size_t)b * CH * TLEN + t;
  const float* y = yy + (size_t)b * CH * TLEN + t;
  float s = 0.f, s2 = 0.f;
  for (int c = 0; c < CH; ++c) {
    float v = r[(size_t)c * TLEN] + y[(size_t)c * TLEN];
    s += v; s2 += v * v;
  }
  float m = s * (1.f / CH);
  float var = s2 * (1.f / CH) - m * m;
  float rs = rsqrtf(var + EPSV);
  float* o = out + (size_t)b * CH * TLEN + t;
  for (int c = 0; c < CH; ++c) {
    float v = r[(size_t)c * TLEN] + y[(size_t)c * TLEN];
    o[(size_t)c * TLEN] = g[c] * (v - m) * rs + bt[c];
  }
}

// ---------------- flash attention with banded rel-pos bias ----------------
// grid: (T/32, B*H). Q,K,V,AO layout: [B][C][T] with channel = h*DKH + d.
__global__ __launch_bounds__(256) void flash_kernel(
    const float* __restrict__ Qg, const float* __restrict__ Kg,
    const float* __restrict__ Vg, const float* __restrict__ relk,
    const float* __restrict__ relv, float* __restrict__ AO)
{
  __shared__ __align__(16) float Qs[32][100];
  __shared__ __align__(16) float Ks[32][100];
  __shared__ __align__(16) float Vs[32][100];
  __shared__ float P[32][33];
  __shared__ float mrow[32], lrow[32], arow[32];
  __shared__ float band[32][9];
  __shared__ float qrk[32][9];
  int bh = blockIdx.y;
  int b = bh >> 1, h = bh & 1;
  int t0 = blockIdx.x * 32;
  int tid = threadIdx.x;
  const float scale = 0.10206207261596575f; // 96^-0.5
  const size_t base = ((size_t)b * CH + h * DKH) * TLEN;

  for (int f = tid; f < 32 * DKH; f += 256) {
    int d = f >> 5, q = f & 31;
    Qs[q][d] = Qg[base + (size_t)d * TLEN + t0 + q] * scale;
  }
  if (tid < 32) { mrow[tid] = -1e30f; lrow[tid] = 0.f; }
  for (int f = tid; f < 288; f += 256) band[f / 9][f % 9] = 0.f;
  __syncthreads();

  // per-query dot with the 9 rel_k embeddings (bias lookup table)
  for (int f = tid; f < 288; f += 256) {
    int q = f / 9, dd = f - q * 9;
    float s = 0.f;
    for (int d = 0; d < DKH; ++d) s += Qs[q][d] * relk[dd * DKH + d];
    qrk[q][dd] = s;
  }

  float Oacc[12] = {};
  int q = tid >> 3;
  int sg8 = tid & 7;
  int dgrp = sg8 * 12;
  int s4 = sg8 * 4;

  for (int s0 = 0; s0 < TLEN; s0 += 32) {
    for (int f = tid; f < 32 * DKH; f += 256) {
      int d = f >> 5, s = f & 31;
      Ks[s][d] = Kg[base + (size_t)d * TLEN + s0 + s];
      Vs[s][d] = Vg[base + (size_t)d * TLEN + s0 + s];
    }
    __syncthreads();
    // S tile: each thread 4 scores for row q
    {
      float a0 = 0.f, a1 = 0.f, a2 = 0.f, a3 = 0.f;
      #pragma unroll 6
      for (int d = 0; d < DKH; d += 4) {
        float4 qv = *(float4*)&Qs[q][d];
        float4 k0 = *(float4*)&Ks[s4 + 0][d];
        float4 k1 = *(float4*)&Ks[s4 + 1][d];
        float4 k2 = *(float4*)&Ks[s4 + 2][d];
        float4 k3 = *(float4*)&Ks[s4 + 3][d];
        a0 += qv.x * k0.x + qv.y * k0.y + qv.z * k0.z + qv.w * k0.w;
        a1 += qv.x * k1.x + qv.y * k1.y + qv.z * k1.z + qv.w * k1.w;
        a2 += qv.x * k2.x + qv.y * k2.y + qv.z * k2.z + qv.w * k2.w;
        a3 += qv.x * k3.x + qv.y * k3.y + qv.z * k3.z + qv.w * k3.w;
      }
      int tg = t0 + q;
      float av[4] = {a0, a1, a2, a3};
      #pragma unroll
      for (int j = 0; j < 4; ++j) {
        int sgl = s0 + s4 + j;
        int dlt = sgl - tg;
        float a = av[j];
        if (dlt >= -WIN && dlt <= WIN) a += qrk[q][dlt + WIN];
        P[q][s4 + j] = a;
      }
    }
    __syncthreads();
    if (tid < 32) {
      int r = tid;
      float mo = mrow[r], mn = mo;
      #pragma unroll 8
      for (int s = 0; s < 32; ++s) mn = fmaxf(mn, P[r][s]);
      float al = __expf(mo - mn);
      float ls = 0.f;
      #pragma unroll 8
      for (int s = 0; s < 32; ++s) {
        float p = __expf(P[r][s] - mn);
        P[r][s] = p; ls += p;
      }
      lrow[r] = lrow[r] * al + ls;
      mrow[r] = mn;
      arow[r] = al;
    }
    __syncthreads();
    // band accumulators (unnormalized p at |s-t|<=4), rescaled every tile
    for (int f = tid; f < 288; f += 256) {
      int r = f / 9, dd = f - r * 9;
      float v = band[r][dd] * arow[r];
      int sg = t0 + r + dd - WIN;
      if (sg >= s0 && sg < s0 + 32) v += P[r][sg - s0];
      band[r][dd] = v;
    }
    // PV accumulate
    float alq = arow[q];
    #pragma unroll
    for (int j = 0; j < 12; ++j) Oacc[j] *= alq;
    #pragma unroll 4
    for (int s = 0; s < 32; ++s) {
      float p = P[q][s];
      float4 v0 = *(float4*)&Vs[s][dgrp];
      float4 v1 = *(float4*)&Vs[s][dgrp + 4];
      float4 v2 = *(float4*)&Vs[s][dgrp + 8];
      Oacc[0] += p * v0.x; Oacc[1] += p * v0.y; Oacc[2]  += p * v0.z; Oacc[3]  += p * v0.w;
      Oacc[4] += p * v1.x; Oacc[5] += p * v1.y; Oacc[6]  += p * v1.z; Oacc[7]  += p * v1.w;
      Oacc[8] += p * v2.x; Oacc[9] += p * v2.y; Oacc[10] += p * v2.z; Oacc[11] += p * v2.w;
    }
    __syncthreads();
  }

  float linv = 1.f / lrow[q];
  #pragma unroll
  for (int j = 0; j < 12; ++j) {
    int d = dgrp + j;
    float val = Oacc[j];
    #pragma unroll
    for (int dd = 0; dd < 9; ++dd) val += band[q][dd] * relv[dd * DKH + d];
    AO[base + (size_t)d * TLEN + t0 + q] = val * linv;
  }
}

extern "C" void kernel_launch(void* const* d_in, const int* in_sizes, int n_in,
                              void* d_out, int out_size, void* d_ws, size_t ws_size,
                              hipStream_t stream) {
  (void)in_sizes; (void)n_in; (void)out_size; (void)ws_size;
  const float* x    = (const float*)d_in[0];
  const float* mask = (const float*)d_in[1];
  const float* wq   = (const float*)d_in[2];
  const float* bq   = (const float*)d_in[3];
  const float* wk   = (const float*)d_in[4];
  const float* bk   = (const float*)d_in[5];
  const float* wv   = (const float*)d_in[6];
  const float* bv   = (const float*)d_in[7];
  const float* wo   = (const float*)d_in[8];
  const float* bo   = (const float*)d_in[9];
  const float* relk = (const float*)d_in[10];
  const float* relv = (const float*)d_in[11];
  const float* ln1g = (const float*)d_in[12];
  const float* ln1b = (const float*)d_in[13];
  const float* fw1  = (const float*)d_in[14];
  const float* fb1  = (const float*)d_in[15];
  const float* fw2  = (const float*)d_in[16];
  const float* fb2  = (const float*)d_in[17];
  const float* ln2g = (const float*)d_in[18];
  const float* ln2b = (const float*)d_in[19];

  float* X   = (float*)d_ws;          // [B,C,T]
  float* Qb  = X   + NBCT;
  float* Kb  = Qb  + NBCT;
  float* Vb  = Kb  + NBCT;
  float* AOb = Vb  + NBCT;
  float* Hb  = AOb + NBCT;            // [B,FC,T]
  float* out = (float*)d_out;

  mulmask_kernel<<<NBCT / 256, 256, 0, stream>>>(x, mask, X);
  for (int l = 0; l < LNUM; ++l) {
    dim3 g1(TLEN / 64, CH / 64, BATCH);
    conv1x1_kernel<<<g1, 256, 0, stream>>>(wq + (size_t)l * CH * CH, bq + l * CH, X, Qb, CH, CH);
    conv1x1_kernel<<<g1, 256, 0, stream>>>(wk + (size_t)l * CH * CH, bk + l * CH, X, Kb, CH, CH);
    conv1x1_kernel<<<g1, 256, 0, stream>>>(wv + (size_t)l * CH * CH, bv + l * CH, X, Vb, CH, CH);
    flash_kernel<<<dim3(TLEN / 32, BATCH * NH), 256, 0, stream>>>(
        Qb, Kb, Vb, relk + (size_t)l * 9 * DKH, relv + (size_t)l * 9 * DKH, AOb);
    conv1x1_kernel<<<g1, 256, 0, stream>>>(wo + (size_t)l * CH * CH, bo + l * CH, AOb, Qb, CH, CH);
    ln_kernel<<<BATCH * TLEN / 256, 256, 0, stream>>>(X, Qb, ln1g + l * CH, ln1b + l * CH, X);
    conv1d3_kernel<<<dim3(TLEN / 64, FCH / 64, BATCH), 256, 0, stream>>>(
        fw1 + (size_t)l * FCH * CH * 3, fb1 + l * FCH, X, Hb, FCH, CH, 1);
    conv1d3_kernel<<<dim3(TLEN / 64, CH / 64, BATCH), 256, 0, stream>>>(
        fw2 + (size_t)l * CH * FCH * 3, fb2 + l * CH, Hb, Qb, CH, FCH, 0);
    ln_kernel<<<BATCH * TLEN / 256, 256, 0, stream>>>(X, Qb, ln2g + l * CH, ln2b + l * CH, X);
  }
  mulmask_kernel<<<NBCT / 256, 256, 0, stream>>>(X, mask, out);
}

// Round 3
// 1359.933 us; speedup vs baseline: 5.2827x; 5.2827x over previous
//
#include <hip/hip_runtime.h>

#define LNUM 6
#define CH 192
#define FCH 768
#define NH 2
#define DKH 96
#define WIN 4
#define BATCH 4
#define TLEN 2048
#define EPSV 1e-5f
#define NBCT (BATCH*CH*TLEN)
#define NBFT (BATCH*FCH*TLEN)

typedef __attribute__((ext_vector_type(8))) short bf16x8;
typedef __attribute__((ext_vector_type(4))) float f32x4;
typedef __attribute__((ext_vector_type(8))) unsigned short u16x8;  // 16-byte chunk

__device__ __forceinline__ unsigned short f2bf(float f) {
  unsigned int u = __builtin_bit_cast(unsigned int, f);
  u = (u + 0x7fffu + ((u >> 16) & 1u)) >> 16;
  return (unsigned short)u;
}
__device__ __forceinline__ float bf2f(unsigned short s) {
  return __builtin_bit_cast(float, ((unsigned int)s) << 16);
}

// ---------- weight prep ----------
__global__ __launch_bounds__(256) void cvt_kernel(const float* __restrict__ src,
    unsigned short* __restrict__ dst, int n) {
  int i = blockIdx.x * 256 + threadIdx.x;
  if (i < n) dst[i] = f2bf(src[i]);
}

// src [L][OC][IC][3] -> dst [L][3][OC][IC]
__global__ __launch_bounds__(256) void ffnw_kernel(const float* __restrict__ src,
    unsigned short* __restrict__ dst, int OC, int IC) {
  int total = LNUM * 3 * OC * IC;
  for (int i = blockIdx.x * 256 + threadIdx.x; i < total; i += gridDim.x * 256) {
    int c = i % IC; int t1 = i / IC;
    int f = t1 % OC; int t2 = t1 / OC;
    int kk = t2 % 3; int l = t2 / 3;
    dst[i] = f2bf(src[(((size_t)l * OC + f) * IC + c) * 3 + kk]);
  }
}

// ---------- transpose in: x[B][C][T]*mask -> Xc [B][T][C] f32 + Xbf bf16 ----------
__global__ __launch_bounds__(256) void tin_kernel(const float* __restrict__ x,
    const float* __restrict__ mask, float* __restrict__ Xc, unsigned short* __restrict__ Xbf) {
  __shared__ float ls[32][33];
  int b = blockIdx.z; int c0 = blockIdx.y * 32, t0 = blockIdx.x * 32;
  int tx = threadIdx.x & 31, ty = threadIdx.x >> 5;
  #pragma unroll
  for (int j = 0; j < 4; ++j)
    ls[ty + j * 8][tx] = x[((size_t)b * CH + c0 + ty + j * 8) * TLEN + t0 + tx];
  __syncthreads();
  #pragma unroll
  for (int j = 0; j < 4; ++j) {
    int t = t0 + ty + j * 8;
    float v = ls[tx][ty + j * 8] * mask[b * TLEN + t];
    size_t o = ((size_t)b * TLEN + t) * CH + c0 + tx;
    Xc[o] = v; Xbf[o] = f2bf(v);
  }
}

// ---------- transpose out: Xc [B][T][C] -> out [B][C][T]*mask ----------
__global__ __launch_bounds__(256) void tout_kernel(const float* __restrict__ Xc,
    const float* __restrict__ mask, float* __restrict__ out) {
  __shared__ float ls[32][33];
  int b = blockIdx.z; int c0 = blockIdx.y * 32, t0 = blockIdx.x * 32;
  int tx = threadIdx.x & 31, ty = threadIdx.x >> 5;
  #pragma unroll
  for (int j = 0; j < 4; ++j)
    ls[ty + j * 8][tx] = Xc[((size_t)b * TLEN + t0 + ty + j * 8) * CH + c0 + tx];
  __syncthreads();
  #pragma unroll
  for (int j = 0; j < 4; ++j)
    out[((size_t)b * CH + c0 + ty + j * 8) * TLEN + t0 + tx] =
        ls[tx][ty + j * 8] * mask[b * TLEN + t0 + tx];
}

// ---------- generic MFMA GEMM: Y[t][n] = act((sum_kk sum_k A[t+kk-off][k] * Bw[kk][n][k] + bias[n])*scale)
// OUTMODE: 0 = bf16 [B][T][N], 1 = bf16 [B][N][T] (transposed), 2 = f32 [B][T][N]
template<int OUTMODE, int NSHIFT, int RELU>
__global__ __launch_bounds__(256) void gemm_tc(
    const unsigned short* __restrict__ A, const unsigned short* __restrict__ Bw,
    const float* __restrict__ bias, void* __restrict__ Y, int Cin, int N, float scale)
{
  __shared__ __align__(16) unsigned short As[66][40];
  __shared__ __align__(16) unsigned short Bs[NSHIFT][64][40];
  int b = blockIdx.z;
  int t0 = blockIdx.x * 64, n0 = blockIdx.y * 64;
  int tid = threadIdx.x;
  int w = tid >> 6, lane = tid & 63;
  int wr = w >> 1, wc = w & 1;
  int lr = lane & 15, lg = lane >> 4;
  const unsigned short* Ab = A + (size_t)b * TLEN * Cin;
  f32x4 acc[2][2] = {};
  for (int kc = 0; kc < Cin; kc += 32) {
    for (int f = tid; f < 66 * 4; f += 256) {
      int r = f >> 2, c8 = (f & 3) * 8;
      int tg = t0 - 1 + r;
      u16x8 v = {};
      if (tg >= 0 && tg < TLEN)
        v = *(const u16x8*)&Ab[(size_t)tg * Cin + kc + c8];
      *(u16x8*)&As[r][c8] = v;
    }
    for (int f = tid; f < NSHIFT * 64 * 4; f += 256) {
      int kk = f >> 8, r = (f >> 2) & 63, c8 = (f & 3) * 8;
      *(u16x8*)&Bs[kk][r][c8] =
          *(const u16x8*)&Bw[((size_t)kk * N + n0 + r) * Cin + kc + c8];
    }
    __syncthreads();
    #pragma unroll
    for (int kk = 0; kk < NSHIFT; ++kk) {
      int roff = (NSHIFT == 1) ? 1 : kk;
      bf16x8 a0 = *(const bf16x8*)&As[wr * 32 + lr + roff][lg * 8];
      bf16x8 a1 = *(const bf16x8*)&As[wr * 32 + 16 + lr + roff][lg * 8];
      bf16x8 b0 = *(const bf16x8*)&Bs[kk][wc * 32 + lr][lg * 8];
      bf16x8 b1 = *(const bf16x8*)&Bs[kk][wc * 32 + 16 + lr][lg * 8];
      acc[0][0] = __builtin_amdgcn_mfma_f32_16x16x32_bf16(a0, b0, acc[0][0], 0, 0, 0);
      acc[0][1] = __builtin_amdgcn_mfma_f32_16x16x32_bf16(a0, b1, acc[0][1], 0, 0, 0);
      acc[1][0] = __builtin_amdgcn_mfma_f32_16x16x32_bf16(a1, b0, acc[1][0], 0, 0, 0);
      acc[1][1] = __builtin_amdgcn_mfma_f32_16x16x32_bf16(a1, b1, acc[1][1], 0, 0, 0);
    }
    __syncthreads();
  }
  #pragma unroll
  for (int i = 0; i < 2; ++i) {
    #pragma unroll
    for (int j = 0; j < 2; ++j) {
      int n = n0 + wc * 32 + j * 16 + lr;
      float bb = bias[n];
      float vals[4];
      #pragma unroll
      for (int r = 0; r < 4; ++r) {
        float v = (acc[i][j][r] + bb) * scale;
        if (RELU) v = fmaxf(v, 0.f);
        vals[r] = v;
      }
      int trow = t0 + wr * 32 + i * 16 + lg * 4;
      if (OUTMODE == 0) {
        unsigned short* Yp = (unsigned short*)Y + ((size_t)b * TLEN + trow) * N + n;
        #pragma unroll
        for (int r = 0; r < 4; ++r) Yp[(size_t)r * N] = f2bf(vals[r]);
      } else if (OUTMODE == 1) {
        ushort4 pk;
        pk.x = f2bf(vals[0]); pk.y = f2bf(vals[1]); pk.z = f2bf(vals[2]); pk.w = f2bf(vals[3]);
        *(ushort4*)((unsigned short*)Y + ((size_t)b * N + n) * TLEN + trow) = pk;
      } else {
        float* Yp = (float*)Y + ((size_t)b * TLEN + trow) * N + n;
        #pragma unroll
        for (int r = 0; r < 4; ++r) Yp[(size_t)r * N] = vals[r];
      }
    }
  }
}

// ---------- fused residual + channel LayerNorm (channels-last rows) ----------
__global__ __launch_bounds__(256) void ln_cl_kernel(
    const float* __restrict__ res, const float* __restrict__ yy,
    const float* __restrict__ g, const float* __restrict__ bt,
    float* __restrict__ Xc, unsigned short* __restrict__ Xbf)
{
  int row = blockIdx.x * 4 + (threadIdx.x >> 6);
  int lane = threadIdx.x & 63;
  const float* r = res + (size_t)row * CH;
  const float* y = yy + (size_t)row * CH;
  float v[3]; float s = 0.f, s2 = 0.f;
  #pragma unroll
  for (int j = 0; j < 3; ++j) {
    v[j] = r[lane + 64 * j] + y[lane + 64 * j];
    s += v[j]; s2 += v[j] * v[j];
  }
  #pragma unroll
  for (int m = 1; m <= 32; m <<= 1) {
    s += __shfl_xor(s, m, 64);
    s2 += __shfl_xor(s2, m, 64);
  }
  float mean = s * (1.f / CH);
  float var = s2 * (1.f / CH) - mean * mean;
  float rs = rsqrtf(var + EPSV);
  #pragma unroll
  for (int j = 0; j < 3; ++j) {
    int c = lane + 64 * j;
    float o = g[c] * (v[j] - mean) * rs + bt[c];
    size_t idx = (size_t)row * CH + c;
    Xc[idx] = o; Xbf[idx] = f2bf(o);
  }
}

// ---------- MFMA flash attention with banded rel-pos ----------
// Q,K channels-last bf16 [B][T][C]; V channels-first bf16 [B][C][T]; AO channels-last bf16.
__global__ __launch_bounds__(256) void flash_mfma(
    const unsigned short* __restrict__ Qg, const unsigned short* __restrict__ Kg,
    const unsigned short* __restrict__ Vg, const float* __restrict__ relk,
    const float* __restrict__ relv, unsigned short* __restrict__ AO)
{
  __shared__ __align__(16) unsigned short Qs[64][104];
  __shared__ __align__(16) unsigned short Ks[64][104];
  __shared__ __align__(16) unsigned short Vs[96][72];
  __shared__ __align__(16) unsigned short Ps[64][72];
  __shared__ float qrk[64][9];
  __shared__ float bandS[64][9];
  __shared__ float relvS[9 * 96];
  int bh = blockIdx.y; int b = bh >> 1, h = bh & 1;
  int t0 = blockIdx.x * 64;
  int tid = threadIdx.x; int w = tid >> 6; int lane = tid & 63;
  int lr = lane & 15, lg = lane >> 4;
  const unsigned short* Qb = Qg + ((size_t)b * TLEN) * CH + h * DKH;
  const unsigned short* Kb = Kg + ((size_t)b * TLEN) * CH + h * DKH;
  const unsigned short* Vb = Vg + ((size_t)b * CH + h * DKH) * TLEN;

  for (int f = tid; f < 64 * 12; f += 256) {
    int r = f / 12, c8 = (f % 12) * 8;
    *(u16x8*)&Qs[r][c8] = *(const u16x8*)&Qb[(size_t)(t0 + r) * CH + c8];
  }
  for (int f = tid; f < 576; f += 256) bandS[f / 9][f % 9] = -1e30f;
  for (int f = tid; f < 864; f += 256) relvS[f] = relv[f];
  __syncthreads();
  for (int f = tid; f < 576; f += 256) {
    int r = f / 9, dd = f - (f / 9) * 9;
    float s = 0.f;
    #pragma unroll 8
    for (int d = 0; d < DKH; ++d) s += bf2f(Qs[r][d]) * relk[dd * DKH + d];
    qrk[r][dd] = s;
  }
  bf16x8 qf[3];
  #pragma unroll
  for (int kc = 0; kc < 3; ++kc) qf[kc] = *(const bf16x8*)&Qs[w * 16 + lr][kc * 32 + lg * 8];
  float mrow[4], lrow[4];
  #pragma unroll
  for (int r = 0; r < 4; ++r) { mrow[r] = -1e30f; lrow[r] = 0.f; }
  f32x4 oacc[6] = {};

  for (int s0 = 0; s0 < TLEN; s0 += 64) {
    __syncthreads();
    for (int f = tid; f < 64 * 12; f += 256) {
      int r = f / 12, c8 = (f % 12) * 8;
      *(u16x8*)&Ks[r][c8] = *(const u16x8*)&Kb[(size_t)(s0 + r) * CH + c8];
    }
    for (int f = tid; f < 96 * 8; f += 256) {
      int r = f >> 3, c8 = (f & 7) * 8;
      *(u16x8*)&Vs[r][c8] = *(const u16x8*)&Vb[(size_t)r * TLEN + s0 + c8];
    }
    __syncthreads();

    f32x4 sacc[4] = {};
    #pragma unroll
    for (int kc = 0; kc < 3; ++kc) {
      #pragma unroll
      for (int ct = 0; ct < 4; ++ct) {
        bf16x8 kfr = *(const bf16x8*)&Ks[ct * 16 + lr][kc * 32 + lg * 8];
        sacc[ct] = __builtin_amdgcn_mfma_f32_16x16x32_bf16(qf[kc], kfr, sacc[ct], 0, 0, 0);
      }
    }
    float mnew[4];
    #pragma unroll
    for (int r = 0; r < 4; ++r) mnew[r] = mrow[r];
    #pragma unroll
    for (int ct = 0; ct < 4; ++ct) {
      #pragma unroll
      for (int r = 0; r < 4; ++r) {
        int ql = w * 16 + lg * 4 + r;
        int dlt = (s0 + ct * 16 + lr) - (t0 + ql);
        float v = sacc[ct][r];
        if (dlt >= -WIN && dlt <= WIN) {
          v += qrk[ql][dlt + WIN];
          bandS[ql][dlt + WIN] = v;   // store logit; each (row,delta) hit exactly once
        }
        sacc[ct][r] = v;
        mnew[r] = fmaxf(mnew[r], v);
      }
    }
    #pragma unroll
    for (int m = 8; m >= 1; m >>= 1)
      #pragma unroll
      for (int r = 0; r < 4; ++r) mnew[r] = fmaxf(mnew[r], __shfl_xor(mnew[r], m, 64));
    float alpha[4], psum[4];
    #pragma unroll
    for (int r = 0; r < 4; ++r) { alpha[r] = __expf(mrow[r] - mnew[r]); psum[r] = 0.f; }
    #pragma unroll
    for (int ct = 0; ct < 4; ++ct) {
      #pragma unroll
      for (int r = 0; r < 4; ++r) {
        float p = __expf(sacc[ct][r] - mnew[r]);
        sacc[ct][r] = p;
        psum[r] += p;
        Ps[w * 16 + lg * 4 + r][ct * 16 + lr] = f2bf(p);
      }
    }
    #pragma unroll
    for (int m = 8; m >= 1; m >>= 1)
      #pragma unroll
      for (int r = 0; r < 4; ++r) psum[r] += __shfl_xor(psum[r], m, 64);
    #pragma unroll
    for (int r = 0; r < 4; ++r) {
      lrow[r] = lrow[r] * alpha[r] + psum[r];
      mrow[r] = mnew[r];
    }
    #pragma unroll
    for (int dt = 0; dt < 6; ++dt)
      #pragma unroll
      for (int r = 0; r < 4; ++r) oacc[dt][r] *= alpha[r];
    #pragma unroll
    for (int ks = 0; ks < 2; ++ks) {
      bf16x8 pa = *(const bf16x8*)&Ps[w * 16 + lr][ks * 32 + lg * 8];
      #pragma unroll
      for (int dt = 0; dt < 6; ++dt) {
        bf16x8 vf = *(const bf16x8*)&Vs[dt * 16 + lr][ks * 32 + lg * 8];
        oacc[dt] = __builtin_amdgcn_mfma_f32_16x16x32_bf16(pa, vf, oacc[dt], 0, 0, 0);
      }
    }
  }

  float bexp[4][9];
  #pragma unroll
  for (int r = 0; r < 4; ++r) {
    int ql = w * 16 + lg * 4 + r;
    #pragma unroll
    for (int dd = 0; dd < 9; ++dd) bexp[r][dd] = __expf(bandS[ql][dd] - mrow[r]);
  }
  float linv[4];
  #pragma unroll
  for (int r = 0; r < 4; ++r) linv[r] = 1.f / lrow[r];
  #pragma unroll
  for (int dt = 0; dt < 6; ++dt) {
    int d = dt * 16 + lr;
    #pragma unroll
    for (int r = 0; r < 4; ++r) {
      int ql = w * 16 + lg * 4 + r;
      float val = oacc[dt][r];
      #pragma unroll
      for (int dd = 0; dd < 9; ++dd) val += bexp[r][dd] * relvS[dd * 96 + d];
      AO[((size_t)b * TLEN + t0 + ql) * CH + h * DKH + d] = f2bf(val * linv[r]);
    }
  }
}

extern "C" void kernel_launch(void* const* d_in, const int* in_sizes, int n_in,
                              void* d_out, int out_size, void* d_ws, size_t ws_size,
                              hipStream_t stream) {
  (void)in_sizes; (void)n_in; (void)out_size; (void)ws_size;
  const float* x    = (const float*)d_in[0];
  const float* mask = (const float*)d_in[1];
  const float* wq   = (const float*)d_in[2];
  const float* bq   = (const float*)d_in[3];
  const float* wk   = (const float*)d_in[4];
  const float* bk   = (const float*)d_in[5];
  const float* wv   = (const float*)d_in[6];
  const float* bv   = (const float*)d_in[7];
  const float* wo   = (const float*)d_in[8];
  const float* bo   = (const float*)d_in[9];
  const float* relk = (const float*)d_in[10];
  const float* relv = (const float*)d_in[11];
  const float* ln1g = (const float*)d_in[12];
  const float* ln1b = (const float*)d_in[13];
  const float* fw1  = (const float*)d_in[14];
  const float* fb1  = (const float*)d_in[15];
  const float* fw2  = (const float*)d_in[16];
  const float* fb2  = (const float*)d_in[17];
  const float* ln2g = (const float*)d_in[18];
  const float* ln2b = (const float*)d_in[19];

  char* p = (char*)d_ws;
  float* Xc = (float*)p;              p += (size_t)NBCT * 4;
  unsigned short* Xbf  = (unsigned short*)p; p += (size_t)NBCT * 2;
  unsigned short* Qbf  = (unsigned short*)p; p += (size_t)NBCT * 2;
  unsigned short* Kbf  = (unsigned short*)p; p += (size_t)NBCT * 2;
  unsigned short* Vbf  = (unsigned short*)p; p += (size_t)NBCT * 2;
  unsigned short* AObf = (unsigned short*)p; p += (size_t)NBCT * 2;
  float* Yo = (float*)p;              p += (size_t)NBCT * 4;
  unsigned short* Hbf  = (unsigned short*)p; p += (size_t)NBFT * 2;
  unsigned short* Wqb  = (unsigned short*)p; p += (size_t)LNUM * CH * CH * 2;
  unsigned short* Wkb  = (unsigned short*)p; p += (size_t)LNUM * CH * CH * 2;
  unsigned short* Wvb  = (unsigned short*)p; p += (size_t)LNUM * CH * CH * 2;
  unsigned short* Wob  = (unsigned short*)p; p += (size_t)LNUM * CH * CH * 2;
  unsigned short* W1b  = (unsigned short*)p; p += (size_t)LNUM * 3 * FCH * CH * 2;
  unsigned short* W2b  = (unsigned short*)p;

  const int nw = LNUM * CH * CH;
  cvt_kernel<<<(nw + 255) / 256, 256, 0, stream>>>(wq, Wqb, nw);
  cvt_kernel<<<(nw + 255) / 256, 256, 0, stream>>>(wk, Wkb, nw);
  cvt_kernel<<<(nw + 255) / 256, 256, 0, stream>>>(wv, Wvb, nw);
  cvt_kernel<<<(nw + 255) / 256, 256, 0, stream>>>(wo, Wob, nw);
  ffnw_kernel<<<2048, 256, 0, stream>>>(fw1, W1b, FCH, CH);
  ffnw_kernel<<<2048, 256, 0, stream>>>(fw2, W2b, CH, FCH);
  tin_kernel<<<dim3(TLEN / 32, CH / 32, BATCH), 256, 0, stream>>>(x, mask, Xc, Xbf);

  const float scale = 0.10206207261596575f;
  for (int l = 0; l < LNUM; ++l) {
    dim3 gp(TLEN / 64, CH / 64, BATCH);
    gemm_tc<0, 1, 0><<<gp, 256, 0, stream>>>(Xbf, Wqb + (size_t)l * CH * CH, bq + l * CH, Qbf, CH, CH, scale);
    gemm_tc<0, 1, 0><<<gp, 256, 0, stream>>>(Xbf, Wkb + (size_t)l * CH * CH, bk + l * CH, Kbf, CH, CH, 1.f);
    gemm_tc<1, 1, 0><<<gp, 256, 0, stream>>>(Xbf, Wvb + (size_t)l * CH * CH, bv + l * CH, Vbf, CH, CH, 1.f);
    flash_mfma<<<dim3(TLEN / 64, BATCH * NH), 256, 0, stream>>>(
        Qbf, Kbf, Vbf, relk + (size_t)l * 9 * DKH, relv + (size_t)l * 9 * DKH, AObf);
    gemm_tc<2, 1, 0><<<gp, 256, 0, stream>>>(AObf, Wob + (size_t)l * CH * CH, bo + l * CH, Yo, CH, CH, 1.f);
    ln_cl_kernel<<<BATCH * TLEN / 4, 256, 0, stream>>>(Xc, Yo, ln1g + l * CH, ln1b + l * CH, Xc, Xbf);
    gemm_tc<0, 3, 1><<<dim3(TLEN / 64, FCH / 64, BATCH), 256, 0, stream>>>(
        Xbf, W1b + (size_t)l * 3 * FCH * CH, fb1 + l * FCH, Hbf, CH, FCH, 1.f);
    gemm_tc<2, 3, 0><<<dim3(TLEN / 64, CH / 64, BATCH), 256, 0, stream>>>(
        Hbf, W2b + (size_t)l * 3 * CH * FCH, fb2 + l * CH, Yo, FCH, CH, 1.f);
    ln_cl_kernel<<<BATCH * TLEN / 4, 256, 0, stream>>>(Xc, Yo, ln2g + l * CH, ln2b + l * CH, Xc, Xbf);
  }
  tout_kernel<<<dim3(TLEN / 32, CH / 32, BATCH), 256, 0, stream>>>(Xc, mask, (float*)d_out);
}

// Round 4
// 924.620 us; speedup vs baseline: 7.7698x; 1.4708x over previous
//
#include <hip/hip_runtime.h>

#define LNUM 6
#define CH 192
#define FCH 768
#define NH 2
#define DKH 96
#define WIN 4
#define BATCH 4
#define TLEN 2048
#define EPSV 1e-5f
#define SCH 4
#define CHUNK (TLEN / SCH)
#define NBCT (BATCH*CH*TLEN)
#define NBFT (BATCH*FCH*TLEN)
#define BHT (BATCH*NH*TLEN)    // 16384

typedef __attribute__((ext_vector_type(8))) short bf16x8;
typedef __attribute__((ext_vector_type(4))) float f32x4;
typedef __attribute__((ext_vector_type(8))) unsigned short u16x8;

__device__ __forceinline__ unsigned short f2bf(float f) {
  unsigned int u = __builtin_bit_cast(unsigned int, f);
  u = (u + 0x7fffu + ((u >> 16) & 1u)) >> 16;
  return (unsigned short)u;
}
__device__ __forceinline__ float bf2f(unsigned short s) {
  return __builtin_bit_cast(float, ((unsigned int)s) << 16);
}

// ---------- weight prep ----------
__global__ __launch_bounds__(256) void cvt_kernel(const float* __restrict__ src,
    unsigned short* __restrict__ dst, int n) {
  int i = blockIdx.x * 256 + threadIdx.x;
  if (i < n) dst[i] = f2bf(src[i]);
}

// fused QKV weights: Wqkv[l][n][c], n<192=Q(*scale),<384=K,else V ; bias too
__global__ __launch_bounds__(256) void prep_qkv(
    const float* __restrict__ wq, const float* __restrict__ wk, const float* __restrict__ wv,
    const float* __restrict__ bq, const float* __restrict__ bk, const float* __restrict__ bv,
    unsigned short* __restrict__ Wqkv, float* __restrict__ Bqkv) {
  const float scale = 0.10206207261596575f;
  int total = LNUM * 576 * CH;
  for (int i = blockIdx.x * 256 + threadIdx.x; i < total; i += gridDim.x * 256) {
    int c = i % CH; int n = (i / CH) % 576; int l = i / (CH * 576);
    float sc = (n < 192) ? scale : 1.f;
    const float* src = (n < 192) ? wq : (n < 384) ? wk : wv;
    int nn = n % 192;
    Wqkv[i] = f2bf(src[((size_t)l * CH + nn) * CH + c] * sc);
    if (c == 0) {
      const float* bs = (n < 192) ? bq : (n < 384) ? bk : bv;
      Bqkv[l * 576 + n] = bs[l * CH + nn] * sc;
    }
  }
}

// src [L][OC][IC][3] -> dst [L][3][OC][IC]
__global__ __launch_bounds__(256) void ffnw_kernel(const float* __restrict__ src,
    unsigned short* __restrict__ dst, int OC, int IC) {
  int total = LNUM * 3 * OC * IC;
  for (int i = blockIdx.x * 256 + threadIdx.x; i < total; i += gridDim.x * 256) {
    int c = i % IC; int t1 = i / IC;
    int f = t1 % OC; int t2 = t1 / OC;
    int kk = t2 % 3; int l = t2 / 3;
    dst[i] = f2bf(src[(((size_t)l * OC + f) * IC + c) * 3 + kk]);
  }
}

// ---------- transpose in/out ----------
__global__ __launch_bounds__(256) void tin_kernel(const float* __restrict__ x,
    const float* __restrict__ mask, float* __restrict__ Xc, unsigned short* __restrict__ Xbf) {
  __shared__ float ls[32][33];
  int b = blockIdx.z; int c0 = blockIdx.y * 32, t0 = blockIdx.x * 32;
  int tx = threadIdx.x & 31, ty = threadIdx.x >> 5;
  #pragma unroll
  for (int j = 0; j < 4; ++j)
    ls[ty + j * 8][tx] = x[((size_t)b * CH + c0 + ty + j * 8) * TLEN + t0 + tx];
  __syncthreads();
  #pragma unroll
  for (int j = 0; j < 4; ++j) {
    int t = t0 + ty + j * 8;
    float v = ls[tx][ty + j * 8] * mask[b * TLEN + t];
    size_t o = ((size_t)b * TLEN + t) * CH + c0 + tx;
    Xc[o] = v; Xbf[o] = f2bf(v);
  }
}

__global__ __launch_bounds__(256) void tout_kernel(const float* __restrict__ Xc,
    const float* __restrict__ mask, float* __restrict__ out) {
  __shared__ float ls[32][33];
  int b = blockIdx.z; int c0 = blockIdx.y * 32, t0 = blockIdx.x * 32;
  int tx = threadIdx.x & 31, ty = threadIdx.x >> 5;
  #pragma unroll
  for (int j = 0; j < 4; ++j)
    ls[ty + j * 8][tx] = Xc[((size_t)b * TLEN + t0 + ty + j * 8) * CH + c0 + tx];
  __syncthreads();
  #pragma unroll
  for (int j = 0; j < 4; ++j)
    out[((size_t)b * CH + c0 + ty + j * 8) * TLEN + t0 + tx] =
        ls[tx][ty + j * 8] * mask[b * TLEN + t0 + tx];
}

// ---------- generic MFMA GEMM, BK=64 ----------
// OUTMODE: 0=bf16 [B][T][N], 2=f32 [B][T][N] (+ks*NBCT), 3=QKV fused epilogue
template<int OUTMODE, int NSHIFT, int RELU, int KSPLIT>
__global__ __launch_bounds__(256) void gemm_tc(
    const unsigned short* __restrict__ A, const unsigned short* __restrict__ Bw,
    const float* __restrict__ bias, void* __restrict__ Y, int Cin, int N)
{
  constexpr int HALO = (NSHIFT == 3) ? 1 : 0;
  constexpr int AROWS = 64 + 2 * HALO;
  __shared__ __align__(16) unsigned short As[AROWS][72];
  __shared__ __align__(16) unsigned short Bs[NSHIFT][64][72];
  int zz = blockIdx.z;
  int b = zz / KSPLIT, ks = zz % KSPLIT;
  int t0 = blockIdx.x * 64, n0 = blockIdx.y * 64;
  int tid = threadIdx.x;
  int w = tid >> 6, lane = tid & 63;
  int wr = w >> 1, wc = w & 1;
  int lr = lane & 15, lg = lane >> 4;
  const unsigned short* Ab = A + (size_t)b * TLEN * Cin;
  int klen = Cin / KSPLIT, k0 = ks * klen;
  f32x4 acc[2][2] = {};
  for (int kc = k0; kc < k0 + klen; kc += 64) {
    for (int f = tid; f < AROWS * 8; f += 256) {
      int r = f >> 3, c8 = (f & 7) * 8;
      int tg = t0 - HALO + r;
      u16x8 v = {};
      if (!HALO || (tg >= 0 && tg < TLEN))
        v = *(const u16x8*)&Ab[(size_t)tg * Cin + kc + c8];
      *(u16x8*)&As[r][c8] = v;
    }
    for (int f = tid; f < NSHIFT * 64 * 8; f += 256) {
      int kk = f >> 9, r = (f >> 3) & 63, c8 = (f & 7) * 8;
      *(u16x8*)&Bs[kk][r][c8] =
          *(const u16x8*)&Bw[((size_t)kk * N + n0 + r) * Cin + kc + c8];
    }
    __syncthreads();
    #pragma unroll
    for (int kk = 0; kk < NSHIFT; ++kk) {
      #pragma unroll
      for (int k2 = 0; k2 < 2; ++k2) {
        bf16x8 a0 = *(const bf16x8*)&As[wr * 32 + lr + kk][k2 * 32 + lg * 8];
        bf16x8 a1 = *(const bf16x8*)&As[wr * 32 + 16 + lr + kk][k2 * 32 + lg * 8];
        bf16x8 b0 = *(const bf16x8*)&Bs[kk][wc * 32 + lr][k2 * 32 + lg * 8];
        bf16x8 b1 = *(const bf16x8*)&Bs[kk][wc * 32 + 16 + lr][k2 * 32 + lg * 8];
        acc[0][0] = __builtin_amdgcn_mfma_f32_16x16x32_bf16(a0, b0, acc[0][0], 0, 0, 0);
        acc[0][1] = __builtin_amdgcn_mfma_f32_16x16x32_bf16(a0, b1, acc[0][1], 0, 0, 0);
        acc[1][0] = __builtin_amdgcn_mfma_f32_16x16x32_bf16(a1, b0, acc[1][0], 0, 0, 0);
        acc[1][1] = __builtin_amdgcn_mfma_f32_16x16x32_bf16(a1, b1, acc[1][1], 0, 0, 0);
      }
    }
    __syncthreads();
  }
  #pragma unroll
  for (int i = 0; i < 2; ++i) {
    #pragma unroll
    for (int j = 0; j < 2; ++j) {
      int n = n0 + wc * 32 + j * 16 + lr;
      float bb = (ks == 0) ? bias[n] : 0.f;
      float vals[4];
      #pragma unroll
      for (int r = 0; r < 4; ++r) {
        float v = acc[i][j][r] + bb;
        if (RELU) v = fmaxf(v, 0.f);
        vals[r] = v;
      }
      int trow = t0 + wr * 32 + i * 16 + lg * 4;
      if (OUTMODE == 0) {
        unsigned short* Yp = (unsigned short*)Y + ((size_t)b * TLEN + trow) * N + n;
        #pragma unroll
        for (int r = 0; r < 4; ++r) Yp[(size_t)r * N] = f2bf(vals[r]);
      } else if (OUTMODE == 2) {
        float* Yp = (float*)Y + (size_t)ks * NBCT + ((size_t)b * TLEN + trow) * N + n;
        #pragma unroll
        for (int r = 0; r < 4; ++r) Yp[(size_t)r * N] = vals[r];
      } else {  // QKV fused: n tile uniform within one of Q/K/V
        unsigned short* base = (unsigned short*)Y;
        if (n0 < 192) {
          unsigned short* Yp = base + ((size_t)b * TLEN + trow) * CH + n;
          #pragma unroll
          for (int r = 0; r < 4; ++r) Yp[(size_t)r * CH] = f2bf(vals[r]);
        } else if (n0 < 384) {
          unsigned short* Yp = base + (size_t)NBCT + ((size_t)b * TLEN + trow) * CH + (n - 192);
          #pragma unroll
          for (int r = 0; r < 4; ++r) Yp[(size_t)r * CH] = f2bf(vals[r]);
        } else {
          ushort4 pk;
          pk.x = f2bf(vals[0]); pk.y = f2bf(vals[1]); pk.z = f2bf(vals[2]); pk.w = f2bf(vals[3]);
          *(ushort4*)(base + 2 * (size_t)NBCT + ((size_t)b * CH + (n - 384)) * TLEN + trow) = pk;
        }
      }
    }
  }
}

// ---------- fused residual + channel LayerNorm ----------
template<int NY>
__global__ __launch_bounds__(256) void ln_cl_kernel(
    const float* __restrict__ res, const float* __restrict__ y0,
    const float* __restrict__ y1, const float* __restrict__ g,
    const float* __restrict__ bt, float* __restrict__ Xc, unsigned short* __restrict__ Xbf)
{
  int row = blockIdx.x * 4 + (threadIdx.x >> 6);
  int lane = threadIdx.x & 63;
  const float* r = res + (size_t)row * CH;
  const float* ya = y0 + (size_t)row * CH;
  const float* yb = (NY == 2) ? y1 + (size_t)row * CH : nullptr;
  float v[3]; float s = 0.f, s2 = 0.f;
  #pragma unroll
  for (int j = 0; j < 3; ++j) {
    float t = r[lane + 64 * j] + ya[lane + 64 * j];
    if (NY == 2) t += yb[lane + 64 * j];
    v[j] = t; s += t; s2 += t * t;
  }
  #pragma unroll
  for (int m = 1; m <= 32; m <<= 1) {
    s += __shfl_xor(s, m, 64);
    s2 += __shfl_xor(s2, m, 64);
  }
  float mean = s * (1.f / CH);
  float var = s2 * (1.f / CH) - mean * mean;
  float rs = rsqrtf(var + EPSV);
  #pragma unroll
  for (int j = 0; j < 3; ++j) {
    int c = lane + 64 * j;
    float o = g[c] * (v[j] - mean) * rs + bt[c];
    size_t idx = (size_t)row * CH + c;
    Xc[idx] = o; Xbf[idx] = f2bf(o);
  }
}

// ---------- flash attention partial (s-chunked) ----------
__global__ __launch_bounds__(256) void flash_part(
    const unsigned short* __restrict__ Qg, const unsigned short* __restrict__ Kg,
    const unsigned short* __restrict__ Vg, const float* __restrict__ relk,
    float* __restrict__ Opart, float* __restrict__ mG, float* __restrict__ lG,
    float* __restrict__ bandG)
{
  __shared__ __align__(16) unsigned short KsB[64 * 104];
  __shared__ __align__(16) unsigned short QV[96 * 72];   // Qs[64][104] then Vs[96][72]
  __shared__ __align__(16) unsigned short Ps[64][72];
  __shared__ float qrk[64][9];
  int bh = blockIdx.y; int b = bh >> 1, h = bh & 1;
  int t0 = blockIdx.x * 64;
  int c0 = blockIdx.z * CHUNK;
  int tid = threadIdx.x; int w = tid >> 6, lane = tid & 63;
  int lr = lane & 15, lg = lane >> 4;
  const unsigned short* Qb = Qg + (size_t)b * TLEN * CH + h * DKH;
  const unsigned short* Kb = Kg + (size_t)b * TLEN * CH + h * DKH;
  const unsigned short* Vb = Vg + ((size_t)b * CH + h * DKH) * TLEN;
  unsigned short (*Qs)[104] = (unsigned short(*)[104])QV;
  unsigned short (*Vs)[72] = (unsigned short(*)[72])QV;
  unsigned short (*Ks)[104] = (unsigned short(*)[104])KsB;

  for (int f = tid; f < 64 * 12; f += 256) {
    int r = f / 12, c8 = (f % 12) * 8;
    *(u16x8*)&Qs[r][c8] = *(const u16x8*)&Qb[(size_t)(t0 + r) * CH + c8];
  }
  __syncthreads();
  bool overlap = (t0 + 64 + WIN > c0) && (t0 - WIN < c0 + CHUNK);
  if (overlap) {
    for (int f = tid; f < 576; f += 256) {
      int r = f / 9, dd = f - (f / 9) * 9;
      float s = 0.f;
      #pragma unroll 8
      for (int d = 0; d < DKH; ++d) s += bf2f(Qs[r][d]) * relk[dd * DKH + d];
      qrk[r][dd] = s;
    }
  }
  bf16x8 qf[3];
  #pragma unroll
  for (int kc = 0; kc < 3; ++kc) qf[kc] = *(const bf16x8*)&Qs[w * 16 + lr][kc * 32 + lg * 8];
  float mrow[4], lrow[4];
  #pragma unroll
  for (int r = 0; r < 4; ++r) { mrow[r] = -1e30f; lrow[r] = 0.f; }
  f32x4 oacc[6] = {};

  for (int it = 0; it < CHUNK / 64; ++it) {
    int s0 = c0 + it * 64;
    __syncthreads();   // protects Qs (iter 0) / previous-iter LDS reads
    for (int f = tid; f < 64 * 12; f += 256) {
      int r = f / 12, c8 = (f % 12) * 8;
      *(u16x8*)&Ks[r][c8] = *(const u16x8*)&Kb[(size_t)(s0 + r) * CH + c8];
    }
    for (int f = tid; f < 96 * 8; f += 256) {
      int r = f >> 3, c8 = (f & 7) * 8;
      *(u16x8*)&Vs[r][c8] = *(const u16x8*)&Vb[(size_t)r * TLEN + s0 + c8];
    }
    __syncthreads();

    f32x4 sacc[4] = {};
    #pragma unroll
    for (int kc = 0; kc < 3; ++kc) {
      #pragma unroll
      for (int ct = 0; ct < 4; ++ct) {
        bf16x8 kfr = *(const bf16x8*)&Ks[ct * 16 + lr][kc * 32 + lg * 8];
        sacc[ct] = __builtin_amdgcn_mfma_f32_16x16x32_bf16(qf[kc], kfr, sacc[ct], 0, 0, 0);
      }
    }
    float mnew[4];
    #pragma unroll
    for (int r = 0; r < 4; ++r) mnew[r] = mrow[r];
    #pragma unroll
    for (int ct = 0; ct < 4; ++ct) {
      #pragma unroll
      for (int r = 0; r < 4; ++r) {
        int ql = w * 16 + lg * 4 + r;
        int dlt = (s0 + ct * 16 + lr) - (t0 + ql);
        float v = sacc[ct][r];
        if (dlt >= -WIN && dlt <= WIN) {
          v += qrk[ql][dlt + WIN];
          bandG[((size_t)bh * TLEN + t0 + ql) * 9 + dlt + WIN] = v;  // logit, exactly-once
        }
        sacc[ct][r] = v;
        mnew[r] = fmaxf(mnew[r], v);
      }
    }
    #pragma unroll
    for (int m = 8; m >= 1; m >>= 1)
      #pragma unroll
      for (int r = 0; r < 4; ++r) mnew[r] = fmaxf(mnew[r], __shfl_xor(mnew[r], m, 64));
    float alpha[4], psum[4];
    #pragma unroll
    for (int r = 0; r < 4; ++r) { alpha[r] = __expf(mrow[r] - mnew[r]); psum[r] = 0.f; }
    #pragma unroll
    for (int ct = 0; ct < 4; ++ct) {
      #pragma unroll
      for (int r = 0; r < 4; ++r) {
        float p = __expf(sacc[ct][r] - mnew[r]);
        sacc[ct][r] = p;
        psum[r] += p;
        Ps[w * 16 + lg * 4 + r][ct * 16 + lr] = f2bf(p);
      }
    }
    #pragma unroll
    for (int m = 8; m >= 1; m >>= 1)
      #pragma unroll
      for (int r = 0; r < 4; ++r) psum[r] += __shfl_xor(psum[r], m, 64);
    #pragma unroll
    for (int r = 0; r < 4; ++r) {
      lrow[r] = lrow[r] * alpha[r] + psum[r];
      mrow[r] = mnew[r];
    }
    #pragma unroll
    for (int dt = 0; dt < 6; ++dt)
      #pragma unroll
      for (int r = 0; r < 4; ++r) oacc[dt][r] *= alpha[r];
    #pragma unroll
    for (int ks = 0; ks < 2; ++ks) {
      bf16x8 pa = *(const bf16x8*)&Ps[w * 16 + lr][ks * 32 + lg * 8];
      #pragma unroll
      for (int dt = 0; dt < 6; ++dt) {
        bf16x8 vf = *(const bf16x8*)&Vs[dt * 16 + lr][ks * 32 + lg * 8];
        oacc[dt] = __builtin_amdgcn_mfma_f32_16x16x32_bf16(pa, vf, oacc[dt], 0, 0, 0);
      }
    }
  }

  size_t pbase = ((size_t)blockIdx.z * (BATCH * NH) + bh) * TLEN + t0;
  #pragma unroll
  for (int dt = 0; dt < 6; ++dt)
    #pragma unroll
    for (int r = 0; r < 4; ++r)
      Opart[(pbase + w * 16 + lg * 4 + r) * 96 + dt * 16 + lr] = oacc[dt][r];
  if (lr == 0) {
    #pragma unroll
    for (int r = 0; r < 4; ++r) {
      mG[pbase + w * 16 + lg * 4 + r] = mrow[r];
      lG[pbase + w * 16 + lg * 4 + r] = lrow[r];
    }
  }
}

// ---------- flash combine ----------
__global__ __launch_bounds__(256) void flash_combine(
    const float* __restrict__ Opart, const float* __restrict__ mG,
    const float* __restrict__ lG, const float* __restrict__ bandG,
    const float* __restrict__ relv, unsigned short* __restrict__ AO)
{
  int sub = threadIdx.x >> 7;
  int d = threadIdx.x & 127;
  int row = blockIdx.x * 2 + sub;            // bh*T + t
  int bh = row >> 11, t = row & 2047;
  float mv[SCH], lv[SCH], m = -1e30f;
  #pragma unroll
  for (int c = 0; c < SCH; ++c) {
    mv[c] = mG[(size_t)c * BHT + row];
    lv[c] = lG[(size_t)c * BHT + row];
    m = fmaxf(m, mv[c]);
  }
  float L = 0.f, e[SCH];
  #pragma unroll
  for (int c = 0; c < SCH; ++c) { e[c] = __expf(mv[c] - m); L += lv[c] * e[c]; }
  if (d < 96) {
    float acc = 0.f;
    #pragma unroll
    for (int c = 0; c < SCH; ++c)
      acc += Opart[((size_t)c * BHT + row) * 96 + d] * e[c];
    #pragma unroll
    for (int dd = 0; dd < 9; ++dd) {
      int s = t + dd - WIN;
      if (s >= 0 && s < TLEN)
        acc += __expf(bandG[(size_t)row * 9 + dd] - m) * relv[dd * 96 + d];
    }
    int b = bh >> 1, h = bh & 1;
    AO[((size_t)b * TLEN + t) * CH + h * DKH + d] = f2bf(acc / L);
  }
}

extern "C" void kernel_launch(void* const* d_in, const int* in_sizes, int n_in,
                              void* d_out, int out_size, void* d_ws, size_t ws_size,
                              hipStream_t stream) {
  (void)in_sizes; (void)n_in; (void)out_size; (void)ws_size;
  const float* x    = (const float*)d_in[0];
  const float* mask = (const float*)d_in[1];
  const float* wq   = (const float*)d_in[2];
  const float* bq   = (const float*)d_in[3];
  const float* wk   = (const float*)d_in[4];
  const float* bk   = (const float*)d_in[5];
  const float* wv   = (const float*)d_in[6];
  const float* bv   = (const float*)d_in[7];
  const float* wo   = (const float*)d_in[8];
  const float* bo   = (const float*)d_in[9];
  const float* relk = (const float*)d_in[10];
  const float* relv = (const float*)d_in[11];
  const float* ln1g = (const float*)d_in[12];
  const float* ln1b = (const float*)d_in[13];
  const float* fw1  = (const float*)d_in[14];
  const float* fb1  = (const float*)d_in[15];
  const float* fw2  = (const float*)d_in[16];
  const float* fb2  = (const float*)d_in[17];
  const float* ln2g = (const float*)d_in[18];
  const float* ln2b = (const float*)d_in[19];

  char* p = (char*)d_ws;
  float* Xc = (float*)p;                      p += (size_t)NBCT * 4;
  unsigned short* Xbf  = (unsigned short*)p;  p += (size_t)NBCT * 2;
  unsigned short* Qbf  = (unsigned short*)p;  p += (size_t)NBCT * 2;  // K,V contiguous after Q
  unsigned short* Kbf  = (unsigned short*)p;  p += (size_t)NBCT * 2;
  unsigned short* Vbf  = (unsigned short*)p;  p += (size_t)NBCT * 2;
  unsigned short* AObf = (unsigned short*)p;  p += (size_t)NBCT * 2;
  char* R = p;                                p += (size_t)NBCT * 8 + (size_t)NBFT * 2;
  float* Yo  = (float*)R;                               // [B][T][C] f32 (ks=0)
  float* Opart = (float*)R;                             // overlays Yo|Yo2|Hbf
  unsigned short* Hbf = (unsigned short*)(R + (size_t)NBCT * 8);
  float* mG = (float*)p;                      p += (size_t)SCH * BHT * 4;
  float* lG = (float*)p;                      p += (size_t)SCH * BHT * 4;
  float* bandG = (float*)p;                   p += (size_t)BHT * 9 * 4;
  unsigned short* Wqkv = (unsigned short*)p;  p += (size_t)LNUM * 576 * CH * 2;
  float* Bqkv = (float*)p;                    p += (size_t)LNUM * 576 * 4;
  unsigned short* Wob  = (unsigned short*)p;  p += (size_t)LNUM * CH * CH * 2;
  unsigned short* W1b  = (unsigned short*)p;  p += (size_t)LNUM * 3 * FCH * CH * 2;
  unsigned short* W2b  = (unsigned short*)p;

  prep_qkv<<<1024, 256, 0, stream>>>(wq, wk, wv, bq, bk, bv, Wqkv, Bqkv);
  const int nw = LNUM * CH * CH;
  cvt_kernel<<<(nw + 255) / 256, 256, 0, stream>>>(wo, Wob, nw);
  ffnw_kernel<<<2048, 256, 0, stream>>>(fw1, W1b, FCH, CH);
  ffnw_kernel<<<2048, 256, 0, stream>>>(fw2, W2b, CH, FCH);
  tin_kernel<<<dim3(TLEN / 32, CH / 32, BATCH), 256, 0, stream>>>(x, mask, Xc, Xbf);

  for (int l = 0; l < LNUM; ++l) {
    gemm_tc<3, 1, 0, 1><<<dim3(32, 9, 4), 256, 0, stream>>>(
        Xbf, Wqkv + (size_t)l * 576 * CH, Bqkv + l * 576, Qbf, CH, 576);
    flash_part<<<dim3(32, 8, SCH), 256, 0, stream>>>(
        Qbf, Kbf, Vbf, relk + (size_t)l * 9 * DKH, Opart, mG, lG, bandG);
    flash_combine<<<BHT / 2, 256, 0, stream>>>(
        Opart, mG, lG, bandG, relv + (size_t)l * 9 * DKH, AObf);
    gemm_tc<2, 1, 0, 1><<<dim3(32, 3, 4), 256, 0, stream>>>(
        AObf, Wob + (size_t)l * CH * CH, bo + l * CH, Yo, CH, CH);
    ln_cl_kernel<1><<<BATCH * TLEN / 4, 256, 0, stream>>>(
        Xc, Yo, nullptr, ln1g + l * CH, ln1b + l * CH, Xc, Xbf);
    gemm_tc<0, 3, 1, 1><<<dim3(32, 12, 4), 256, 0, stream>>>(
        Xbf, W1b + (size_t)l * 3 * FCH * CH, fb1 + l * FCH, Hbf, CH, FCH);
    gemm_tc<2, 3, 0, 2><<<dim3(32, 3, 8), 256, 0, stream>>>(
        Hbf, W2b + (size_t)l * 3 * CH * FCH, fb2 + l * CH, Yo, FCH, CH);
    ln_cl_kernel<2><<<BATCH * TLEN / 4, 256, 0, stream>>>(
        Xc, Yo, Yo + NBCT, ln2g + l * CH, ln2b + l * CH, Xc, Xbf);
  }
  tout_kernel<<<dim3(TLEN / 32, CH / 32, BATCH), 256, 0, stream>>>(Xc, mask, (float*)d_out);
}

// Round 6
// 863.546 us; speedup vs baseline: 8.3193x; 1.0707x over previous
//
#include <hip/hip_runtime.h>

#define LNUM 6
#define CH 192
#define FCH 768
#define NH 2
#define DKH 96
#define WIN 4
#define BATCH 4
#define TLEN 2048
#define EPSV 1e-5f
#define SCH 4
#define CHUNK (TLEN / SCH)
#define NBCT (BATCH*CH*TLEN)
#define NBFT (BATCH*FCH*TLEN)
#define BHT (BATCH*NH*TLEN)    // 16384

typedef __attribute__((ext_vector_type(8))) short bf16x8;
typedef __attribute__((ext_vector_type(4))) float f32x4;
typedef __attribute__((ext_vector_type(8))) unsigned short u16x8;

__device__ __forceinline__ unsigned short f2bf(float f) {
  unsigned int u = __builtin_bit_cast(unsigned int, f);
  u = (u + 0x7fffu + ((u >> 16) & 1u)) >> 16;
  return (unsigned short)u;
}
__device__ __forceinline__ float bf2f(unsigned short s) {
  return __builtin_bit_cast(float, ((unsigned int)s) << 16);
}
__device__ __forceinline__ float exp2a(float x) {   // hardware 2^x, hazard-safe
#if __has_builtin(__builtin_amdgcn_exp2f)
  return __builtin_amdgcn_exp2f(x);
#else
  return exp2f(x);
#endif
}

// ---------- weight prep ----------
__global__ __launch_bounds__(256) void cvt_kernel(const float* __restrict__ src,
    unsigned short* __restrict__ dst, int n) {
  int i = blockIdx.x * 256 + threadIdx.x;
  if (i < n) dst[i] = f2bf(src[i]);
}

// fused QKV weights: Wqkv[l][n][c], n<192=Q(*scale*log2e),<384=K,else V
__global__ __launch_bounds__(256) void prep_qkv(
    const float* __restrict__ wq, const float* __restrict__ wk, const float* __restrict__ wv,
    const float* __restrict__ bq, const float* __restrict__ bk, const float* __restrict__ bv,
    unsigned short* __restrict__ Wqkv, float* __restrict__ Bqkv) {
  const float qscale = 0.10206207261596575f * 1.4426950408889634f;  // dk^-0.5 * log2(e)
  int total = LNUM * 576 * CH;
  for (int i = blockIdx.x * 256 + threadIdx.x; i < total; i += gridDim.x * 256) {
    int c = i % CH; int n = (i / CH) % 576; int l = i / (CH * 576);
    float sc = (n < 192) ? qscale : 1.f;
    const float* src = (n < 192) ? wq : (n < 384) ? wk : wv;
    int nn = n % 192;
    Wqkv[i] = f2bf(src[((size_t)l * CH + nn) * CH + c] * sc);
    if (c == 0) {
      const float* bs = (n < 192) ? bq : (n < 384) ? bk : bv;
      Bqkv[l * 576 + n] = bs[l * CH + nn] * sc;
    }
  }
}

// src [L][OC][IC][3] -> dst [L][3][OC][IC]
__global__ __launch_bounds__(256) void ffnw_kernel(const float* __restrict__ src,
    unsigned short* __restrict__ dst, int OC, int IC) {
  int total = LNUM * 3 * OC * IC;
  for (int i = blockIdx.x * 256 + threadIdx.x; i < total; i += gridDim.x * 256) {
    int c = i % IC; int t1 = i / IC;
    int f = t1 % OC; int t2 = t1 / OC;
    int kk = t2 % 3; int l = t2 / 3;
    dst[i] = f2bf(src[(((size_t)l * OC + f) * IC + c) * 3 + kk]);
  }
}

// ---------- transpose in/out ----------
__global__ __launch_bounds__(256) void tin_kernel(const float* __restrict__ x,
    const float* __restrict__ mask, float* __restrict__ Xc, unsigned short* __restrict__ Xbf) {
  __shared__ float ls[32][33];
  int b = blockIdx.z; int c0 = blockIdx.y * 32, t0 = blockIdx.x * 32;
  int tx = threadIdx.x & 31, ty = threadIdx.x >> 5;
  #pragma unroll
  for (int j = 0; j < 4; ++j)
    ls[ty + j * 8][tx] = x[((size_t)b * CH + c0 + ty + j * 8) * TLEN + t0 + tx];
  __syncthreads();
  #pragma unroll
  for (int j = 0; j < 4; ++j) {
    int t = t0 + ty + j * 8;
    float v = ls[tx][ty + j * 8] * mask[b * TLEN + t];
    size_t o = ((size_t)b * TLEN + t) * CH + c0 + tx;
    Xc[o] = v; Xbf[o] = f2bf(v);
  }
}

__global__ __launch_bounds__(256) void tout_kernel(const float* __restrict__ Xc,
    const float* __restrict__ mask, float* __restrict__ out) {
  __shared__ float ls[32][33];
  int b = blockIdx.z; int c0 = blockIdx.y * 32, t0 = blockIdx.x * 32;
  int tx = threadIdx.x & 31, ty = threadIdx.x >> 5;
  #pragma unroll
  for (int j = 0; j < 4; ++j)
    ls[ty + j * 8][tx] = Xc[((size_t)b * TLEN + t0 + ty + j * 8) * CH + c0 + tx];
  __syncthreads();
  #pragma unroll
  for (int j = 0; j < 4; ++j)
    out[((size_t)b * CH + c0 + ty + j * 8) * TLEN + t0 + tx] =
        ls[tx][ty + j * 8] * mask[b * TLEN + t0 + tx];
}

// ---------- generic MFMA GEMM, BK=64, M-tile = MFR*32 ----------
// OUTMODE: 0=bf16 [B][T][N], 2=f32 [B][T][N] (+ks*NBCT), 3=QKV fused epilogue
template<int OUTMODE, int NSHIFT, int RELU, int KSPLIT, int MFR>
__global__ __launch_bounds__(256) void gemm_tc(
    const unsigned short* __restrict__ A, const unsigned short* __restrict__ Bw,
    const float* __restrict__ bias, void* __restrict__ Y, int Cin, int N)
{
  constexpr int HALO = (NSHIFT == 3) ? 1 : 0;
  constexpr int AROWS = MFR * 32 + 2 * HALO;
  __shared__ __align__(16) unsigned short As[AROWS][72];
  __shared__ __align__(16) unsigned short Bs[NSHIFT][64][72];
  int zz = blockIdx.z;
  int b = zz / KSPLIT, ks = zz % KSPLIT;
  int t0 = blockIdx.x * (MFR * 32), n0 = blockIdx.y * 64;
  int tid = threadIdx.x;
  int w = tid >> 6, lane = tid & 63;
  int wr = w >> 1, wc = w & 1;
  int lr = lane & 15, lg = lane >> 4;
  const unsigned short* Ab = A + (size_t)b * TLEN * Cin;
  int klen = Cin / KSPLIT, k0 = ks * klen;
  f32x4 acc[MFR][2] = {};
  for (int kc = k0; kc < k0 + klen; kc += 64) {
    for (int f = tid; f < AROWS * 8; f += 256) {
      int r = f >> 3, c8 = (f & 7) * 8;
      int tg = t0 - HALO + r;
      u16x8 v = {};
      if (!HALO || (tg >= 0 && tg < TLEN))
        v = *(const u16x8*)&Ab[(size_t)tg * Cin + kc + c8];
      *(u16x8*)&As[r][c8] = v;
    }
    for (int f = tid; f < NSHIFT * 64 * 8; f += 256) {
      int kk = f >> 9, r = (f >> 3) & 63, c8 = (f & 7) * 8;
      *(u16x8*)&Bs[kk][r][c8] =
          *(const u16x8*)&Bw[((size_t)kk * N + n0 + r) * Cin + kc + c8];
    }
    __syncthreads();
    #pragma unroll
    for (int kk = 0; kk < NSHIFT; ++kk) {
      #pragma unroll
      for (int k2 = 0; k2 < 2; ++k2) {
        bf16x8 b0 = *(const bf16x8*)&Bs[kk][wc * 32 + lr][k2 * 32 + lg * 8];
        bf16x8 b1 = *(const bf16x8*)&Bs[kk][wc * 32 + 16 + lr][k2 * 32 + lg * 8];
        #pragma unroll
        for (int i = 0; i < MFR; ++i) {
          bf16x8 a = *(const bf16x8*)&As[wr * MFR * 16 + i * 16 + lr + kk][k2 * 32 + lg * 8];
          acc[i][0] = __builtin_amdgcn_mfma_f32_16x16x32_bf16(a, b0, acc[i][0], 0, 0, 0);
          acc[i][1] = __builtin_amdgcn_mfma_f32_16x16x32_bf16(a, b1, acc[i][1], 0, 0, 0);
        }
      }
    }
    __syncthreads();
  }
  #pragma unroll
  for (int i = 0; i < MFR; ++i) {
    #pragma unroll
    for (int j = 0; j < 2; ++j) {
      int n = n0 + wc * 32 + j * 16 + lr;
      float bb = (ks == 0) ? bias[n] : 0.f;
      float vals[4];
      #pragma unroll
      for (int r = 0; r < 4; ++r) {
        float v = acc[i][j][r] + bb;
        if (RELU) v = fmaxf(v, 0.f);
        vals[r] = v;
      }
      int trow = t0 + wr * MFR * 16 + i * 16 + lg * 4;
      if (OUTMODE == 0) {
        unsigned short* Yp = (unsigned short*)Y + ((size_t)b * TLEN + trow) * N + n;
        #pragma unroll
        for (int r = 0; r < 4; ++r) Yp[(size_t)r * N] = f2bf(vals[r]);
      } else if (OUTMODE == 2) {
        float* Yp = (float*)Y + (size_t)ks * NBCT + ((size_t)b * TLEN + trow) * N + n;
        #pragma unroll
        for (int r = 0; r < 4; ++r) Yp[(size_t)r * N] = vals[r];
      } else {  // QKV fused: n tile uniform within one of Q/K/V
        unsigned short* base = (unsigned short*)Y;
        if (n0 < 192) {
          unsigned short* Yp = base + ((size_t)b * TLEN + trow) * CH + n;
          #pragma unroll
          for (int r = 0; r < 4; ++r) Yp[(size_t)r * CH] = f2bf(vals[r]);
        } else if (n0 < 384) {
          unsigned short* Yp = base + (size_t)NBCT + ((size_t)b * TLEN + trow) * CH + (n - 192);
          #pragma unroll
          for (int r = 0; r < 4; ++r) Yp[(size_t)r * CH] = f2bf(vals[r]);
        } else {
          ushort4 pk;
          pk.x = f2bf(vals[0]); pk.y = f2bf(vals[1]); pk.z = f2bf(vals[2]); pk.w = f2bf(vals[3]);
          *(ushort4*)(base + 2 * (size_t)NBCT + ((size_t)b * CH + (n - 384)) * TLEN + trow) = pk;
        }
      }
    }
  }
}

// ---------- fused residual + channel LayerNorm ----------
template<int NY>
__global__ __launch_bounds__(256) void ln_cl_kernel(
    const float* __restrict__ res, const float* __restrict__ y0,
    const float* __restrict__ y1, const float* __restrict__ g,
    const float* __restrict__ bt, float* __restrict__ Xc, unsigned short* __restrict__ Xbf)
{
  int row = blockIdx.x * 4 + (threadIdx.x >> 6);
  int lane = threadIdx.x & 63;
  const float* r = res + (size_t)row * CH;
  const float* ya = y0 + (size_t)row * CH;
  const float* yb = (NY == 2) ? y1 + (size_t)row * CH : nullptr;
  float v[3]; float s = 0.f, s2 = 0.f;
  #pragma unroll
  for (int j = 0; j < 3; ++j) {
    float t = r[lane + 64 * j] + ya[lane + 64 * j];
    if (NY == 2) t += yb[lane + 64 * j];
    v[j] = t; s += t; s2 += t * t;
  }
  #pragma unroll
  for (int m = 1; m <= 32; m <<= 1) {
    s += __shfl_xor(s, m, 64);
    s2 += __shfl_xor(s2, m, 64);
  }
  float mean = s * (1.f / CH);
  float var = s2 * (1.f / CH) - mean * mean;
  float rs = rsqrtf(var + EPSV);
  #pragma unroll
  for (int j = 0; j < 3; ++j) {
    int c = lane + 64 * j;
    float o = g[c] * (v[j] - mean) * rs + bt[c];
    size_t idx = (size_t)row * CH + c;
    Xc[idx] = o; Xbf[idx] = f2bf(o);
  }
}

// ---------- flash attention partial (s-chunked, swapped-QK, base-2) ----------
__global__ __launch_bounds__(256, 4) void flash_part(
    const unsigned short* __restrict__ Qg, const unsigned short* __restrict__ Kg,
    const unsigned short* __restrict__ Vg, const float* __restrict__ relk,
    float* __restrict__ Opart, float* __restrict__ mG, float* __restrict__ lG,
    float* __restrict__ bandG)
{
  __shared__ __align__(16) unsigned short KsB[64 * 104];
  __shared__ __align__(16) unsigned short QV[96 * 72];   // Qs[64][104] then Vs[96][72]
  __shared__ __align__(16) unsigned short Ps[64][72];
  __shared__ float qrk[64][9];
  int bh = blockIdx.y; int b = bh >> 1, h = bh & 1;
  int t0 = blockIdx.x * 64;
  int c0 = blockIdx.z * CHUNK;
  int tid = threadIdx.x; int w = tid >> 6, lane = tid & 63;
  int lr = lane & 15, lg = lane >> 4;
  int q = w * 16 + lr;                 // this thread's softmax-state query row
  const unsigned short* Qb = Qg + (size_t)b * TLEN * CH + h * DKH;
  const unsigned short* Kb = Kg + (size_t)b * TLEN * CH + h * DKH;
  const unsigned short* Vb = Vg + ((size_t)b * CH + h * DKH) * TLEN;
  unsigned short (*Qs)[104] = (unsigned short(*)[104])QV;
  unsigned short (*Vs)[72] = (unsigned short(*)[72])QV;
  unsigned short (*Ks)[104] = (unsigned short(*)[104])KsB;

  for (int f = tid; f < 64 * 12; f += 256) {
    int r = f / 12, c8 = (f % 12) * 8;
    *(u16x8*)&Qs[r][c8] = *(const u16x8*)&Qb[(size_t)(t0 + r) * CH + c8];
  }
  __syncthreads();
  bool overlap = (t0 + 64 + WIN > c0) && (t0 - WIN < c0 + CHUNK);
  if (overlap) {
    for (int f = tid; f < 576; f += 256) {
      int r = f / 9, dd = f - (f / 9) * 9;
      float s = 0.f;
      #pragma unroll 8
      for (int d = 0; d < DKH; ++d) s += bf2f(Qs[r][d]) * relk[dd * DKH + d];
      qrk[r][dd] = s;    // already in base-2 domain (Q pre-scaled by log2e)
    }
  }
  bf16x8 qf[3];
  #pragma unroll
  for (int kc = 0; kc < 3; ++kc) qf[kc] = *(const bf16x8*)&Qs[q][kc * 32 + lg * 8];
  float mrow = -1e30f, lrow = 0.f;
  f32x4 oacc[6] = {};

  for (int it = 0; it < CHUNK / 64; ++it) {
    int s0 = c0 + it * 64;
    __syncthreads();
    for (int f = tid; f < 64 * 12; f += 256) {
      int r = f / 12, c8 = (f % 12) * 8;
      *(u16x8*)&Ks[r][c8] = *(const u16x8*)&Kb[(size_t)(s0 + r) * CH + c8];
    }
    for (int f = tid; f < 96 * 8; f += 256) {
      int r = f >> 3, c8 = (f & 7) * 8;
      *(u16x8*)&Vs[r][c8] = *(const u16x8*)&Vb[(size_t)r * TLEN + s0 + c8];
    }
    __syncthreads();

    // S^T tile: sacc[ct][r] = S[s = ct*16+lg*4+r][q]
    f32x4 sacc[4] = {};
    #pragma unroll
    for (int kc = 0; kc < 3; ++kc) {
      #pragma unroll
      for (int ct = 0; ct < 4; ++ct) {
        bf16x8 kfr = *(const bf16x8*)&Ks[ct * 16 + lr][kc * 32 + lg * 8];
        sacc[ct] = __builtin_amdgcn_mfma_f32_16x16x32_bf16(kfr, qf[kc], sacc[ct], 0, 0, 0);
      }
    }
    // band bias (only on diagonal-overlapping tiles; block-uniform predicate)
    if (s0 + 64 + WIN > t0 && s0 < t0 + 64 + WIN) {
      #pragma unroll
      for (int ct = 0; ct < 4; ++ct)
        #pragma unroll
        for (int r = 0; r < 4; ++r) {
          int dlt = (s0 + ct * 16 + lg * 4 + r) - (t0 + q);
          if (dlt >= -WIN && dlt <= WIN) {
            float v = sacc[ct][r] + qrk[q][dlt + WIN];
            sacc[ct][r] = v;
            bandG[((size_t)bh * TLEN + t0 + q) * 9 + dlt + WIN] = v;  // logit, exactly-once
          }
        }
    }
    float cm[4];
    #pragma unroll
    for (int ct = 0; ct < 4; ++ct)
      cm[ct] = fmaxf(fmaxf(sacc[ct][0], sacc[ct][1]), fmaxf(sacc[ct][2], sacc[ct][3]));
    float mnew = fmaxf(mrow, fmaxf(fmaxf(cm[0], cm[1]), fmaxf(cm[2], cm[3])));
    mnew = fmaxf(mnew, __shfl_xor(mnew, 16, 64));
    mnew = fmaxf(mnew, __shfl_xor(mnew, 32, 64));
    float alpha = exp2a(mrow - mnew);      // alpha for q = w*16+lr
    float psum = 0.f;
    #pragma unroll
    for (int ct = 0; ct < 4; ++ct) {
      float p0 = exp2a(sacc[ct][0] - mnew), p1 = exp2a(sacc[ct][1] - mnew);
      float p2 = exp2a(sacc[ct][2] - mnew), p3 = exp2a(sacc[ct][3] - mnew);
      psum += (p0 + p1) + (p2 + p3);
      ushort4 pk;
      pk.x = f2bf(p0); pk.y = f2bf(p1); pk.z = f2bf(p2); pk.w = f2bf(p3);
      *(ushort4*)&Ps[q][ct * 16 + lg * 4] = pk;
    }
    psum += __shfl_xor(psum, 16, 64);
    psum += __shfl_xor(psum, 32, 64);
    lrow = lrow * alpha + psum;
    mrow = mnew;
    // oacc rows are q_out = w*16 + lg*4 + r -> need THOSE rows' alphas.
    // Row j's alpha lives at wave-lane j (lg=0, lr=j), j = lg*4+r < 16.
    float alo[4];
    #pragma unroll
    for (int r = 0; r < 4; ++r) alo[r] = __shfl(alpha, lg * 4 + r, 64);
    #pragma unroll
    for (int dt = 0; dt < 6; ++dt)
      #pragma unroll
      for (int r = 0; r < 4; ++r) oacc[dt][r] *= alo[r];
    #pragma unroll
    for (int ks = 0; ks < 2; ++ks) {
      bf16x8 pa = *(const bf16x8*)&Ps[q][ks * 32 + lg * 8];
      #pragma unroll
      for (int dt = 0; dt < 6; ++dt) {
        bf16x8 vf = *(const bf16x8*)&Vs[dt * 16 + lr][ks * 32 + lg * 8];
        oacc[dt] = __builtin_amdgcn_mfma_f32_16x16x32_bf16(pa, vf, oacc[dt], 0, 0, 0);
      }
    }
  }

  size_t pbase = ((size_t)blockIdx.z * (BATCH * NH) + bh) * TLEN + t0;
  #pragma unroll
  for (int dt = 0; dt < 6; ++dt)
    #pragma unroll
    for (int r = 0; r < 4; ++r)
      Opart[(pbase + w * 16 + lg * 4 + r) * 96 + dt * 16 + lr] = oacc[dt][r];
  if (lg == 0) {
    mG[pbase + q] = mrow;
    lG[pbase + q] = lrow;
  }
}

// ---------- flash combine (base-2) ----------
__global__ __launch_bounds__(256) void flash_combine(
    const float* __restrict__ Opart, const float* __restrict__ mG,
    const float* __restrict__ lG, const float* __restrict__ bandG,
    const float* __restrict__ relv, unsigned short* __restrict__ AO)
{
  int sub = threadIdx.x >> 7;
  int d = threadIdx.x & 127;
  int row = blockIdx.x * 2 + sub;            // bh*T + t
  int bh = row >> 11, t = row & 2047;
  float mv[SCH], lv[SCH], m = -1e30f;
  #pragma unroll
  for (int c = 0; c < SCH; ++c) {
    mv[c] = mG[(size_t)c * BHT + row];
    lv[c] = lG[(size_t)c * BHT + row];
    m = fmaxf(m, mv[c]);
  }
  float L = 0.f, e[SCH];
  #pragma unroll
  for (int c = 0; c < SCH; ++c) { e[c] = exp2a(mv[c] - m); L += lv[c] * e[c]; }
  if (d < 96) {
    float acc = 0.f;
    #pragma unroll
    for (int c = 0; c < SCH; ++c)
      acc += Opart[((size_t)c * BHT + row) * 96 + d] * e[c];
    #pragma unroll
    for (int dd = 0; dd < 9; ++dd) {
      int s = t + dd - WIN;
      if (s >= 0 && s < TLEN)
        acc += exp2a(bandG[(size_t)row * 9 + dd] - m) * relv[dd * 96 + d];
    }
    int b = bh >> 1, h = bh & 1;
    AO[((size_t)b * TLEN + t) * CH + h * DKH + d] = f2bf(acc / L);
  }
}

extern "C" void kernel_launch(void* const* d_in, const int* in_sizes, int n_in,
                              void* d_out, int out_size, void* d_ws, size_t ws_size,
                              hipStream_t stream) {
  (void)in_sizes; (void)n_in; (void)out_size; (void)ws_size;
  const float* x    = (const float*)d_in[0];
  const float* mask = (const float*)d_in[1];
  const float* wq   = (const float*)d_in[2];
  const float* bq   = (const float*)d_in[3];
  const float* wk   = (const float*)d_in[4];
  const float* bk   = (const float*)d_in[5];
  const float* wv   = (const float*)d_in[6];
  const float* bv   = (const float*)d_in[7];
  const float* wo   = (const float*)d_in[8];
  const float* bo   = (const float*)d_in[9];
  const float* relk = (const float*)d_in[10];
  const float* relv = (const float*)d_in[11];
  const float* ln1g = (const float*)d_in[12];
  const float* ln1b = (const float*)d_in[13];
  const float* fw1  = (const float*)d_in[14];
  const float* fb1  = (const float*)d_in[15];
  const float* fw2  = (const float*)d_in[16];
  const float* fb2  = (const float*)d_in[17];
  const float* ln2g = (const float*)d_in[18];
  const float* ln2b = (const float*)d_in[19];

  char* p = (char*)d_ws;
  float* Xc = (float*)p;                      p += (size_t)NBCT * 4;
  unsigned short* Xbf  = (unsigned short*)p;  p += (size_t)NBCT * 2;
  unsigned short* Qbf  = (unsigned short*)p;  p += (size_t)NBCT * 2;  // K,V contiguous after Q
  unsigned short* Kbf  = (unsigned short*)p;  p += (size_t)NBCT * 2;
  unsigned short* Vbf  = (unsigned short*)p;  p += (size_t)NBCT * 2;
  unsigned short* AObf = (unsigned short*)p;  p += (size_t)NBCT * 2;
  char* R = p;                                p += (size_t)NBCT * 8 + (size_t)NBFT * 2;
  float* Yo  = (float*)R;                               // [B][T][C] f32 (ks=0)
  float* Opart = (float*)R;                             // overlays Yo|Yo2|Hbf
  unsigned short* Hbf = (unsigned short*)(R + (size_t)NBCT * 8);
  float* mG = (float*)p;                      p += (size_t)SCH * BHT * 4;
  float* lG = (float*)p;                      p += (size_t)SCH * BHT * 4;
  float* bandG = (float*)p;                   p += (size_t)BHT * 9 * 4;
  unsigned short* Wqkv = (unsigned short*)p;  p += (size_t)LNUM * 576 * CH * 2;
  float* Bqkv = (float*)p;                    p += (size_t)LNUM * 576 * 4;
  unsigned short* Wob  = (unsigned short*)p;  p += (size_t)LNUM * CH * CH * 2;
  unsigned short* W1b  = (unsigned short*)p;  p += (size_t)LNUM * 3 * FCH * CH * 2;
  unsigned short* W2b  = (unsigned short*)p;

  prep_qkv<<<1024, 256, 0, stream>>>(wq, wk, wv, bq, bk, bv, Wqkv, Bqkv);
  const int nw = LNUM * CH * CH;
  cvt_kernel<<<(nw + 255) / 256, 256, 0, stream>>>(wo, Wob, nw);
  ffnw_kernel<<<2048, 256, 0, stream>>>(fw1, W1b, FCH, CH);
  ffnw_kernel<<<2048, 256, 0, stream>>>(fw2, W2b, CH, FCH);
  tin_kernel<<<dim3(TLEN / 32, CH / 32, BATCH), 256, 0, stream>>>(x, mask, Xc, Xbf);

  for (int l = 0; l < LNUM; ++l) {
    gemm_tc<3, 1, 0, 1, 4><<<dim3(16, 9, 4), 256, 0, stream>>>(
        Xbf, Wqkv + (size_t)l * 576 * CH, Bqkv + l * 576, Qbf, CH, 576);
    flash_part<<<dim3(32, 8, SCH), 256, 0, stream>>>(
        Qbf, Kbf, Vbf, relk + (size_t)l * 9 * DKH, Opart, mG, lG, bandG);
    flash_combine<<<BHT / 2, 256, 0, stream>>>(
        Opart, mG, lG, bandG, relv + (size_t)l * 9 * DKH, AObf);
    gemm_tc<2, 1, 0, 1, 2><<<dim3(32, 3, 4), 256, 0, stream>>>(
        AObf, Wob + (size_t)l * CH * CH, bo + l * CH, Yo, CH, CH);
    ln_cl_kernel<1><<<BATCH * TLEN / 4, 256, 0, stream>>>(
        Xc, Yo, nullptr, ln1g + l * CH, ln1b + l * CH, Xc, Xbf);
    gemm_tc<0, 3, 1, 1, 4><<<dim3(16, 12, 4), 256, 0, stream>>>(
        Xbf, W1b + (size_t)l * 3 * FCH * CH, fb1 + l * FCH, Hbf, CH, FCH);
    gemm_tc<2, 3, 0, 2, 2><<<dim3(32, 3, 8), 256, 0, stream>>>(
        Hbf, W2b + (size_t)l * 3 * CH * FCH, fb2 + l * CH, Yo, FCH, CH);
    ln_cl_kernel<2><<<BATCH * TLEN / 4, 256, 0, stream>>>(
        Xc, Yo, Yo + NBCT, ln2g + l * CH, ln2b + l * CH, Xc, Xbf);
  }
  tout_kernel<<<dim3(TLEN / 32, CH / 32, BATCH), 256, 0, stream>>>(Xc, mask, (float*)d_out);
}

// Round 7
// 784.680 us; speedup vs baseline: 9.1554x; 1.1005x over previous
//
#include <hip/hip_runtime.h>

#define LNUM 6
#define CH 192
#define FCH 768
#define NH 2
#define DKH 96
#define WIN 4
#define BATCH 4
#define TLEN 2048
#define EPSV 1e-5f
#define SCH 4
#define CHUNK (TLEN / SCH)
#define NBCT (BATCH*CH*TLEN)
#define NBFT (BATCH*FCH*TLEN)
#define BHT (BATCH*NH*TLEN)    // 16384

typedef __attribute__((ext_vector_type(8))) short bf16x8;
typedef __attribute__((ext_vector_type(4))) float f32x4;
typedef __attribute__((ext_vector_type(8))) unsigned short u16x8;

__device__ __forceinline__ unsigned short f2bf(float f) {
  unsigned int u = __builtin_bit_cast(unsigned int, f);
  u = (u + 0x7fffu + ((u >> 16) & 1u)) >> 16;
  return (unsigned short)u;
}
__device__ __forceinline__ float bf2f(unsigned short s) {
  return __builtin_bit_cast(float, ((unsigned int)s) << 16);
}
__device__ __forceinline__ float exp2a(float x) {   // hardware 2^x, hazard-safe
#if __has_builtin(__builtin_amdgcn_exp2f)
  return __builtin_amdgcn_exp2f(x);
#else
  return exp2f(x);
#endif
}

// ---------- weight prep ----------
__global__ __launch_bounds__(256) void cvt_kernel(const float* __restrict__ src,
    unsigned short* __restrict__ dst, int n) {
  int i = blockIdx.x * 256 + threadIdx.x;
  if (i < n) dst[i] = f2bf(src[i]);
}

// fused QKV weights: Wqkv[l][n][c], n<192=Q(*scale*log2e),<384=K,else V
__global__ __launch_bounds__(256) void prep_qkv(
    const float* __restrict__ wq, const float* __restrict__ wk, const float* __restrict__ wv,
    const float* __restrict__ bq, const float* __restrict__ bk, const float* __restrict__ bv,
    unsigned short* __restrict__ Wqkv, float* __restrict__ Bqkv) {
  const float qscale = 0.10206207261596575f * 1.4426950408889634f;  // dk^-0.5 * log2(e)
  int total = LNUM * 576 * CH;
  for (int i = blockIdx.x * 256 + threadIdx.x; i < total; i += gridDim.x * 256) {
    int c = i % CH; int n = (i / CH) % 576; int l = i / (CH * 576);
    float sc = (n < 192) ? qscale : 1.f;
    const float* src = (n < 192) ? wq : (n < 384) ? wk : wv;
    int nn = n % 192;
    Wqkv[i] = f2bf(src[((size_t)l * CH + nn) * CH + c] * sc);
    if (c == 0) {
      const float* bs = (n < 192) ? bq : (n < 384) ? bk : bv;
      Bqkv[l * 576 + n] = bs[l * CH + nn] * sc;
    }
  }
}

// src [L][OC][IC][3] -> dst [L][3][OC][IC]
__global__ __launch_bounds__(256) void ffnw_kernel(const float* __restrict__ src,
    unsigned short* __restrict__ dst, int OC, int IC) {
  int total = LNUM * 3 * OC * IC;
  for (int i = blockIdx.x * 256 + threadIdx.x; i < total; i += gridDim.x * 256) {
    int c = i % IC; int t1 = i / IC;
    int f = t1 % OC; int t2 = t1 / OC;
    int kk = t2 % 3; int l = t2 / 3;
    dst[i] = f2bf(src[(((size_t)l * OC + f) * IC + c) * 3 + kk]);
  }
}

// ---------- transpose in/out ----------
__global__ __launch_bounds__(256) void tin_kernel(const float* __restrict__ x,
    const float* __restrict__ mask, float* __restrict__ Xc, unsigned short* __restrict__ Xbf) {
  __shared__ float ls[32][33];
  int b = blockIdx.z; int c0 = blockIdx.y * 32, t0 = blockIdx.x * 32;
  int tx = threadIdx.x & 31, ty = threadIdx.x >> 5;
  #pragma unroll
  for (int j = 0; j < 4; ++j)
    ls[ty + j * 8][tx] = x[((size_t)b * CH + c0 + ty + j * 8) * TLEN + t0 + tx];
  __syncthreads();
  #pragma unroll
  for (int j = 0; j < 4; ++j) {
    int t = t0 + ty + j * 8;
    float v = ls[tx][ty + j * 8] * mask[b * TLEN + t];
    size_t o = ((size_t)b * TLEN + t) * CH + c0 + tx;
    Xc[o] = v; Xbf[o] = f2bf(v);
  }
}

__global__ __launch_bounds__(256) void tout_kernel(const float* __restrict__ Xc,
    const float* __restrict__ mask, float* __restrict__ out) {
  __shared__ float ls[32][33];
  int b = blockIdx.z; int c0 = blockIdx.y * 32, t0 = blockIdx.x * 32;
  int tx = threadIdx.x & 31, ty = threadIdx.x >> 5;
  #pragma unroll
  for (int j = 0; j < 4; ++j)
    ls[ty + j * 8][tx] = Xc[((size_t)b * TLEN + t0 + ty + j * 8) * CH + c0 + tx];
  __syncthreads();
  #pragma unroll
  for (int j = 0; j < 4; ++j)
    out[((size_t)b * CH + c0 + ty + j * 8) * TLEN + t0 + tx] =
        ls[tx][ty + j * 8] * mask[b * TLEN + t0 + tx];
}

// ---------- generic MFMA GEMM, BK=64, M-tile = MFR*32 ----------
// OUTMODE: 0=bf16 [B][T][N], 2=f32 [B][T][N] (+ks*NBCT), 3=QKV fused epilogue
template<int OUTMODE, int NSHIFT, int RELU, int KSPLIT, int MFR>
__global__ __launch_bounds__(256) void gemm_tc(
    const unsigned short* __restrict__ A, const unsigned short* __restrict__ Bw,
    const float* __restrict__ bias, void* __restrict__ Y, int Cin, int N)
{
  constexpr int HALO = (NSHIFT == 3) ? 1 : 0;
  constexpr int AROWS = MFR * 32 + 2 * HALO;
  __shared__ __align__(16) unsigned short As[AROWS][72];
  __shared__ __align__(16) unsigned short Bs[NSHIFT][64][72];
  int zz = blockIdx.z;
  int b = zz / KSPLIT, ks = zz % KSPLIT;
  int t0 = blockIdx.x * (MFR * 32), n0 = blockIdx.y * 64;
  int tid = threadIdx.x;
  int w = tid >> 6, lane = tid & 63;
  int wr = w >> 1, wc = w & 1;
  int lr = lane & 15, lg = lane >> 4;
  const unsigned short* Ab = A + (size_t)b * TLEN * Cin;
  int klen = Cin / KSPLIT, k0 = ks * klen;
  f32x4 acc[MFR][2] = {};
  for (int kc = k0; kc < k0 + klen; kc += 64) {
    for (int f = tid; f < AROWS * 8; f += 256) {
      int r = f >> 3, c8 = (f & 7) * 8;
      int tg = t0 - HALO + r;
      u16x8 v = {};
      if (!HALO || (tg >= 0 && tg < TLEN))
        v = *(const u16x8*)&Ab[(size_t)tg * Cin + kc + c8];
      *(u16x8*)&As[r][c8] = v;
    }
    for (int f = tid; f < NSHIFT * 64 * 8; f += 256) {
      int kk = f >> 9, r = (f >> 3) & 63, c8 = (f & 7) * 8;
      *(u16x8*)&Bs[kk][r][c8] =
          *(const u16x8*)&Bw[((size_t)kk * N + n0 + r) * Cin + kc + c8];
    }
    __syncthreads();
    #pragma unroll
    for (int kk = 0; kk < NSHIFT; ++kk) {
      #pragma unroll
      for (int k2 = 0; k2 < 2; ++k2) {
        bf16x8 b0 = *(const bf16x8*)&Bs[kk][wc * 32 + lr][k2 * 32 + lg * 8];
        bf16x8 b1 = *(const bf16x8*)&Bs[kk][wc * 32 + 16 + lr][k2 * 32 + lg * 8];
        #pragma unroll
        for (int i = 0; i < MFR; ++i) {
          bf16x8 a = *(const bf16x8*)&As[wr * MFR * 16 + i * 16 + lr + kk][k2 * 32 + lg * 8];
          acc[i][0] = __builtin_amdgcn_mfma_f32_16x16x32_bf16(a, b0, acc[i][0], 0, 0, 0);
          acc[i][1] = __builtin_amdgcn_mfma_f32_16x16x32_bf16(a, b1, acc[i][1], 0, 0, 0);
        }
      }
    }
    __syncthreads();
  }
  #pragma unroll
  for (int i = 0; i < MFR; ++i) {
    #pragma unroll
    for (int j = 0; j < 2; ++j) {
      int n = n0 + wc * 32 + j * 16 + lr;
      float bb = (ks == 0) ? bias[n] : 0.f;
      float vals[4];
      #pragma unroll
      for (int r = 0; r < 4; ++r) {
        float v = acc[i][j][r] + bb;
        if (RELU) v = fmaxf(v, 0.f);
        vals[r] = v;
      }
      int trow = t0 + wr * MFR * 16 + i * 16 + lg * 4;
      if (OUTMODE == 0) {
        unsigned short* Yp = (unsigned short*)Y + ((size_t)b * TLEN + trow) * N + n;
        #pragma unroll
        for (int r = 0; r < 4; ++r) Yp[(size_t)r * N] = f2bf(vals[r]);
      } else if (OUTMODE == 2) {
        float* Yp = (float*)Y + (size_t)ks * NBCT + ((size_t)b * TLEN + trow) * N + n;
        #pragma unroll
        for (int r = 0; r < 4; ++r) Yp[(size_t)r * N] = vals[r];
      } else {  // QKV fused: n tile uniform within one of Q/K/V
        unsigned short* base = (unsigned short*)Y;
        if (n0 < 192) {
          unsigned short* Yp = base + ((size_t)b * TLEN + trow) * CH + n;
          #pragma unroll
          for (int r = 0; r < 4; ++r) Yp[(size_t)r * CH] = f2bf(vals[r]);
        } else if (n0 < 384) {
          unsigned short* Yp = base + (size_t)NBCT + ((size_t)b * TLEN + trow) * CH + (n - 192);
          #pragma unroll
          for (int r = 0; r < 4; ++r) Yp[(size_t)r * CH] = f2bf(vals[r]);
        } else {
          ushort4 pk;
          pk.x = f2bf(vals[0]); pk.y = f2bf(vals[1]); pk.z = f2bf(vals[2]); pk.w = f2bf(vals[3]);
          *(ushort4*)(base + 2 * (size_t)NBCT + ((size_t)b * CH + (n - 384)) * TLEN + trow) = pk;
        }
      }
    }
  }
}

// ---------- fused residual + channel LayerNorm ----------
template<int NY>
__global__ __launch_bounds__(256) void ln_cl_kernel(
    const float* __restrict__ res, const float* __restrict__ y0,
    const float* __restrict__ y1, const float* __restrict__ g,
    const float* __restrict__ bt, float* __restrict__ Xc, unsigned short* __restrict__ Xbf)
{
  int row = blockIdx.x * 4 + (threadIdx.x >> 6);
  int lane = threadIdx.x & 63;
  const float* r = res + (size_t)row * CH;
  const float* ya = y0 + (size_t)row * CH;
  const float* yb = (NY == 2) ? y1 + (size_t)row * CH : nullptr;
  float v[3]; float s = 0.f, s2 = 0.f;
  #pragma unroll
  for (int j = 0; j < 3; ++j) {
    float t = r[lane + 64 * j] + ya[lane + 64 * j];
    if (NY == 2) t += yb[lane + 64 * j];
    v[j] = t; s += t; s2 += t * t;
  }
  #pragma unroll
  for (int m = 1; m <= 32; m <<= 1) {
    s += __shfl_xor(s, m, 64);
    s2 += __shfl_xor(s2, m, 64);
  }
  float mean = s * (1.f / CH);
  float var = s2 * (1.f / CH) - mean * mean;
  float rs = rsqrtf(var + EPSV);
  #pragma unroll
  for (int j = 0; j < 3; ++j) {
    int c = lane + 64 * j;
    float o = g[c] * (v[j] - mean) * rs + bt[c];
    size_t idx = (size_t)row * CH + c;
    Xc[idx] = o; Xbf[idx] = f2bf(o);
  }
}

// ---------- flash attention partial (s-chunked, swapped-QK, base-2, dbuf) ----------
__global__ __launch_bounds__(256, 4) void flash_part(
    const unsigned short* __restrict__ Qg, const unsigned short* __restrict__ Kg,
    const unsigned short* __restrict__ Vg, const float* __restrict__ relk,
    float* __restrict__ Opart, float* __restrict__ mG, float* __restrict__ lG,
    float* __restrict__ bandG)
{
  __shared__ __align__(16) unsigned short KsB[64 * 104];
  __shared__ __align__(16) unsigned short QV[96 * 72];   // Qs[64][104] then Vs[96][72]
  __shared__ __align__(16) unsigned short Ps[64][72];
  __shared__ float qrk[64][9];
  int bh = blockIdx.y; int b = bh >> 1, h = bh & 1;
  int t0 = blockIdx.x * 64;
  int c0 = blockIdx.z * CHUNK;
  int tid = threadIdx.x; int w = tid >> 6, lane = tid & 63;
  int lr = lane & 15, lg = lane >> 4;
  int q = w * 16 + lr;                 // this thread's softmax-state query row
  const unsigned short* Qb = Qg + (size_t)b * TLEN * CH + h * DKH;
  const unsigned short* Kb = Kg + (size_t)b * TLEN * CH + h * DKH;
  const unsigned short* Vb = Vg + ((size_t)b * CH + h * DKH) * TLEN;
  unsigned short (*Qs)[104] = (unsigned short(*)[104])QV;
  unsigned short (*Vs)[72] = (unsigned short(*)[72])QV;
  unsigned short (*Ks)[104] = (unsigned short(*)[104])KsB;

  // staging index precompute (3 u16x8 per thread for K and for V)
  int kr[3], kc8[3], vr[3], vc8[3];
  #pragma unroll
  for (int j = 0; j < 3; ++j) {
    int f = tid + j * 256;
    kr[j] = f / 12; kc8[j] = (f % 12) * 8;
    vr[j] = f >> 3; vc8[j] = (f & 7) * 8;
  }

  for (int f = tid; f < 64 * 12; f += 256) {
    int r = f / 12, c8 = (f % 12) * 8;
    *(u16x8*)&Qs[r][c8] = *(const u16x8*)&Qb[(size_t)(t0 + r) * CH + c8];
  }
  __syncthreads();
  bool overlap = (t0 + 64 + WIN > c0) && (t0 - WIN < c0 + CHUNK);
  if (overlap) {
    for (int f = tid; f < 576; f += 256) {
      int r = f / 9, dd = f - (f / 9) * 9;
      float s = 0.f;
      #pragma unroll 8
      for (int d = 0; d < DKH; ++d) s += bf2f(Qs[r][d]) * relk[dd * DKH + d];
      qrk[r][dd] = s;    // already in base-2 domain (Q pre-scaled by log2e)
    }
  }
  bf16x8 qf[3];
  #pragma unroll
  for (int kc = 0; kc < 3; ++kc) qf[kc] = *(const bf16x8*)&Qs[q][kc * 32 + lg * 8];
  float mrow = -1e30f, lrow = 0.f;
  f32x4 oacc[6] = {};

  // prologue: prefetch tile 0 into registers
  u16x8 kreg[3], vreg[3];
  #pragma unroll
  for (int j = 0; j < 3; ++j)
    kreg[j] = *(const u16x8*)&Kb[(size_t)(c0 + kr[j]) * CH + kc8[j]];
  #pragma unroll
  for (int j = 0; j < 3; ++j)
    vreg[j] = *(const u16x8*)&Vb[(size_t)vr[j] * TLEN + c0 + vc8[j]];

  for (int it = 0; it < CHUNK / 64; ++it) {
    int s0 = c0 + it * 64;
    __syncthreads();                      // prev compute (and Q use) done
    #pragma unroll
    for (int j = 0; j < 3; ++j) *(u16x8*)&Ks[kr[j]][kc8[j]] = kreg[j];
    #pragma unroll
    for (int j = 0; j < 3; ++j) *(u16x8*)&Vs[vr[j]][vc8[j]] = vreg[j];
    if (it + 1 < CHUNK / 64) {            // issue next tile's loads (hide under compute)
      int sn = s0 + 64;
      #pragma unroll
      for (int j = 0; j < 3; ++j)
        kreg[j] = *(const u16x8*)&Kb[(size_t)(sn + kr[j]) * CH + kc8[j]];
      #pragma unroll
      for (int j = 0; j < 3; ++j)
        vreg[j] = *(const u16x8*)&Vb[(size_t)vr[j] * TLEN + sn + vc8[j]];
    }
    __syncthreads();

    // S^T tile: sacc[ct][r] = S[s = ct*16+lg*4+r][q]
    f32x4 sacc[4] = {};
    __builtin_amdgcn_s_setprio(1);
    #pragma unroll
    for (int kc = 0; kc < 3; ++kc) {
      #pragma unroll
      for (int ct = 0; ct < 4; ++ct) {
        bf16x8 kfr = *(const bf16x8*)&Ks[ct * 16 + lr][kc * 32 + lg * 8];
        sacc[ct] = __builtin_amdgcn_mfma_f32_16x16x32_bf16(kfr, qf[kc], sacc[ct], 0, 0, 0);
      }
    }
    __builtin_amdgcn_s_setprio(0);
    // band bias (only on diagonal-overlapping tiles; block-uniform predicate)
    if (s0 + 64 + WIN > t0 && s0 < t0 + 64 + WIN) {
      #pragma unroll
      for (int ct = 0; ct < 4; ++ct)
        #pragma unroll
        for (int r = 0; r < 4; ++r) {
          int dlt = (s0 + ct * 16 + lg * 4 + r) - (t0 + q);
          if (dlt >= -WIN && dlt <= WIN) {
            float v = sacc[ct][r] + qrk[q][dlt + WIN];
            sacc[ct][r] = v;
            bandG[((size_t)bh * TLEN + t0 + q) * 9 + dlt + WIN] = v;  // logit, exactly-once
          }
        }
    }
    float cm[4];
    #pragma unroll
    for (int ct = 0; ct < 4; ++ct)
      cm[ct] = fmaxf(fmaxf(sacc[ct][0], sacc[ct][1]), fmaxf(sacc[ct][2], sacc[ct][3]));
    float tmax = fmaxf(fmaxf(cm[0], cm[1]), fmaxf(cm[2], cm[3]));
    tmax = fmaxf(tmax, __shfl_xor(tmax, 16, 64));
    tmax = fmaxf(tmax, __shfl_xor(tmax, 32, 64));
    // defer-rescale: skip alpha path if no q in this wave grew past mrow+8
    bool upd = !__all(tmax <= mrow + 8.f);
    float mnew = upd ? fmaxf(mrow, tmax) : mrow;
    float psum = 0.f;
    #pragma unroll
    for (int ct = 0; ct < 4; ++ct) {
      float p0 = exp2a(sacc[ct][0] - mnew), p1 = exp2a(sacc[ct][1] - mnew);
      float p2 = exp2a(sacc[ct][2] - mnew), p3 = exp2a(sacc[ct][3] - mnew);
      psum += (p0 + p1) + (p2 + p3);
      ushort4 pk;
      pk.x = f2bf(p0); pk.y = f2bf(p1); pk.z = f2bf(p2); pk.w = f2bf(p3);
      *(ushort4*)&Ps[q][ct * 16 + lg * 4] = pk;
    }
    psum += __shfl_xor(psum, 16, 64);
    psum += __shfl_xor(psum, 32, 64);
    if (upd) {
      float alpha = exp2a(mrow - mnew);      // alpha for q = w*16+lr
      lrow *= alpha;
      // oacc rows are q_out = w*16 + lg*4 + r -> need THOSE rows' alphas
      float alo[4];
      #pragma unroll
      for (int r = 0; r < 4; ++r) alo[r] = __shfl(alpha, lg * 4 + r, 64);
      #pragma unroll
      for (int dt = 0; dt < 6; ++dt)
        #pragma unroll
        for (int r = 0; r < 4; ++r) oacc[dt][r] *= alo[r];
      mrow = mnew;
    }
    lrow += psum;
    __builtin_amdgcn_s_setprio(1);
    #pragma unroll
    for (int ks = 0; ks < 2; ++ks) {
      bf16x8 pa = *(const bf16x8*)&Ps[q][ks * 32 + lg * 8];
      #pragma unroll
      for (int dt = 0; dt < 6; ++dt) {
        bf16x8 vf = *(const bf16x8*)&Vs[dt * 16 + lr][ks * 32 + lg * 8];
        oacc[dt] = __builtin_amdgcn_mfma_f32_16x16x32_bf16(pa, vf, oacc[dt], 0, 0, 0);
      }
    }
    __builtin_amdgcn_s_setprio(0);
  }

  size_t pbase = ((size_t)blockIdx.z * (BATCH * NH) + bh) * TLEN + t0;
  #pragma unroll
  for (int dt = 0; dt < 6; ++dt)
    #pragma unroll
    for (int r = 0; r < 4; ++r)
      Opart[(pbase + w * 16 + lg * 4 + r) * 96 + dt * 16 + lr] = oacc[dt][r];
  if (lg == 0) {
    mG[pbase + q] = mrow;
    lG[pbase + q] = lrow;
  }
}

// ---------- flash combine (base-2) ----------
__global__ __launch_bounds__(256) void flash_combine(
    const float* __restrict__ Opart, const float* __restrict__ mG,
    const float* __restrict__ lG, const float* __restrict__ bandG,
    const float* __restrict__ relv, unsigned short* __restrict__ AO)
{
  int sub = threadIdx.x >> 7;
  int d = threadIdx.x & 127;
  int row = blockIdx.x * 2 + sub;            // bh*T + t
  int bh = row >> 11, t = row & 2047;
  float mv[SCH], lv[SCH], m = -1e30f;
  #pragma unroll
  for (int c = 0; c < SCH; ++c) {
    mv[c] = mG[(size_t)c * BHT + row];
    lv[c] = lG[(size_t)c * BHT + row];
    m = fmaxf(m, mv[c]);
  }
  float L = 0.f, e[SCH];
  #pragma unroll
  for (int c = 0; c < SCH; ++c) { e[c] = exp2a(mv[c] - m); L += lv[c] * e[c]; }
  if (d < 96) {
    float acc = 0.f;
    #pragma unroll
    for (int c = 0; c < SCH; ++c)
      acc += Opart[((size_t)c * BHT + row) * 96 + d] * e[c];
    #pragma unroll
    for (int dd = 0; dd < 9; ++dd) {
      int s = t + dd - WIN;
      if (s >= 0 && s < TLEN)
        acc += exp2a(bandG[(size_t)row * 9 + dd] - m) * relv[dd * 96 + d];
    }
    int b = bh >> 1, h = bh & 1;
    AO[((size_t)b * TLEN + t) * CH + h * DKH + d] = f2bf(acc / L);
  }
}

extern "C" void kernel_launch(void* const* d_in, const int* in_sizes, int n_in,
                              void* d_out, int out_size, void* d_ws, size_t ws_size,
                              hipStream_t stream) {
  (void)in_sizes; (void)n_in; (void)out_size; (void)ws_size;
  const float* x    = (const float*)d_in[0];
  const float* mask = (const float*)d_in[1];
  const float* wq   = (const float*)d_in[2];
  const float* bq   = (const float*)d_in[3];
  const float* wk   = (const float*)d_in[4];
  const float* bk   = (const float*)d_in[5];
  const float* wv   = (const float*)d_in[6];
  const float* bv   = (const float*)d_in[7];
  const float* wo   = (const float*)d_in[8];
  const float* bo   = (const float*)d_in[9];
  const float* relk = (const float*)d_in[10];
  const float* relv = (const float*)d_in[11];
  const float* ln1g = (const float*)d_in[12];
  const float* ln1b = (const float*)d_in[13];
  const float* fw1  = (const float*)d_in[14];
  const float* fb1  = (const float*)d_in[15];
  const float* fw2  = (const float*)d_in[16];
  const float* fb2  = (const float*)d_in[17];
  const float* ln2g = (const float*)d_in[18];
  const float* ln2b = (const float*)d_in[19];

  char* p = (char*)d_ws;
  float* Xc = (float*)p;                      p += (size_t)NBCT * 4;
  unsigned short* Xbf  = (unsigned short*)p;  p += (size_t)NBCT * 2;
  unsigned short* Qbf  = (unsigned short*)p;  p += (size_t)NBCT * 2;  // K,V contiguous after Q
  unsigned short* Kbf  = (unsigned short*)p;  p += (size_t)NBCT * 2;
  unsigned short* Vbf  = (unsigned short*)p;  p += (size_t)NBCT * 2;
  unsigned short* AObf = (unsigned short*)p;  p += (size_t)NBCT * 2;
  char* R = p;                                p += (size_t)NBCT * 8 + (size_t)NBFT * 2;
  float* Yo  = (float*)R;                               // [B][T][C] f32 (ks=0)
  float* Opart = (float*)R;                             // overlays Yo|Yo2|Hbf
  unsigned short* Hbf = (unsigned short*)(R + (size_t)NBCT * 8);
  float* mG = (float*)p;                      p += (size_t)SCH * BHT * 4;
  float* lG = (float*)p;                      p += (size_t)SCH * BHT * 4;
  float* bandG = (float*)p;                   p += (size_t)BHT * 9 * 4;
  unsigned short* Wqkv = (unsigned short*)p;  p += (size_t)LNUM * 576 * CH * 2;
  float* Bqkv = (float*)p;                    p += (size_t)LNUM * 576 * 4;
  unsigned short* Wob  = (unsigned short*)p;  p += (size_t)LNUM * CH * CH * 2;
  unsigned short* W1b  = (unsigned short*)p;  p += (size_t)LNUM * 3 * FCH * CH * 2;
  unsigned short* W2b  = (unsigned short*)p;

  prep_qkv<<<1024, 256, 0, stream>>>(wq, wk, wv, bq, bk, bv, Wqkv, Bqkv);
  const int nw = LNUM * CH * CH;
  cvt_kernel<<<(nw + 255) / 256, 256, 0, stream>>>(wo, Wob, nw);
  ffnw_kernel<<<2048, 256, 0, stream>>>(fw1, W1b, FCH, CH);
  ffnw_kernel<<<2048, 256, 0, stream>>>(fw2, W2b, CH, FCH);
  tin_kernel<<<dim3(TLEN / 32, CH / 32, BATCH), 256, 0, stream>>>(x, mask, Xc, Xbf);

  for (int l = 0; l < LNUM; ++l) {
    gemm_tc<3, 1, 0, 1, 4><<<dim3(16, 9, 4), 256, 0, stream>>>(
        Xbf, Wqkv + (size_t)l * 576 * CH, Bqkv + l * 576, Qbf, CH, 576);
    flash_part<<<dim3(32, 8, SCH), 256, 0, stream>>>(
        Qbf, Kbf, Vbf, relk + (size_t)l * 9 * DKH, Opart, mG, lG, bandG);
    flash_combine<<<BHT / 2, 256, 0, stream>>>(
        Opart, mG, lG, bandG, relv + (size_t)l * 9 * DKH, AObf);
    gemm_tc<2, 1, 0, 1, 2><<<dim3(32, 3, 4), 256, 0, stream>>>(
        AObf, Wob + (size_t)l * CH * CH, bo + l * CH, Yo, CH, CH);
    ln_cl_kernel<1><<<BATCH * TLEN / 4, 256, 0, stream>>>(
        Xc, Yo, nullptr, ln1g + l * CH, ln1b + l * CH, Xc, Xbf);
    gemm_tc<0, 3, 1, 1, 4><<<dim3(16, 12, 4), 256, 0, stream>>>(
        Xbf, W1b + (size_t)l * 3 * FCH * CH, fb1 + l * FCH, Hbf, CH, FCH);
    gemm_tc<2, 3, 0, 2, 2><<<dim3(32, 3, 8), 256, 0, stream>>>(
        Hbf, W2b + (size_t)l * 3 * CH * FCH, fb2 + l * CH, Yo, FCH, CH);
    ln_cl_kernel<2><<<BATCH * TLEN / 4, 256, 0, stream>>>(
        Xc, Yo, Yo + NBCT, ln2g + l * CH, ln2b + l * CH, Xc, Xbf);
  }
  tout_kernel<<<dim3(TLEN / 32, CH / 32, BATCH), 256, 0, stream>>>(Xc, mask, (float*)d_out);
}

// Round 8
// 656.842 us; speedup vs baseline: 10.9373x; 1.1946x over previous
//
#include <hip/hip_runtime.h>

#define LNUM 6
#define CH 192
#define FCH 768
#define NH 2
#define DKH 96
#define WIN 4
#define BATCH 4
#define TLEN 2048
#define EPSV 1e-5f
#define SCH 4
#define CHUNK (TLEN / SCH)
#define NBCT (BATCH*CH*TLEN)
#define NBFT (BATCH*FCH*TLEN)
#define BHT (BATCH*NH*TLEN)    // 16384

typedef __attribute__((ext_vector_type(8))) short bf16x8;
typedef __attribute__((ext_vector_type(4))) float f32x4;
typedef __attribute__((ext_vector_type(8))) unsigned short u16x8;

__device__ __forceinline__ unsigned short f2bf(float f) {
  unsigned int u = __builtin_bit_cast(unsigned int, f);
  u = (u + 0x7fffu + ((u >> 16) & 1u)) >> 16;
  return (unsigned short)u;
}
__device__ __forceinline__ float bf2f(unsigned short s) {
  return __builtin_bit_cast(float, ((unsigned int)s) << 16);
}
__device__ __forceinline__ float exp2a(float x) {   // hardware 2^x, hazard-safe
#if __has_builtin(__builtin_amdgcn_exp2f)
  return __builtin_amdgcn_exp2f(x);
#else
  return exp2f(x);
#endif
}

// ---------- fused weight prep (QKV fuse+scale, WO cvt, FFN w1/w2 transpose) ----------
__global__ __launch_bounds__(256) void prep_all(
    const float* __restrict__ wq, const float* __restrict__ wk, const float* __restrict__ wv,
    const float* __restrict__ bq, const float* __restrict__ bk, const float* __restrict__ bv,
    const float* __restrict__ wo, const float* __restrict__ fw1, const float* __restrict__ fw2,
    unsigned short* __restrict__ Wqkv, float* __restrict__ Bqkv,
    unsigned short* __restrict__ Wob, unsigned short* __restrict__ W1b,
    unsigned short* __restrict__ W2b)
{
  const float qscale = 0.10206207261596575f * 1.4426950408889634f;  // dk^-0.5 * log2(e)
  const int n0 = LNUM * 576 * CH;            // qkv
  const int n1 = LNUM * CH * CH;             // wo
  const int n2 = LNUM * 3 * FCH * CH;        // w1
  const int n3 = LNUM * 3 * CH * FCH;        // w2
  int total = n0 + n1 + n2 + n3;
  for (int i = blockIdx.x * 256 + threadIdx.x; i < total; i += gridDim.x * 256) {
    if (i < n0) {
      int c = i % CH; int n = (i / CH) % 576; int l = i / (CH * 576);
      float sc = (n < 192) ? qscale : 1.f;
      const float* src = (n < 192) ? wq : (n < 384) ? wk : wv;
      int nn = n % 192;
      Wqkv[i] = f2bf(src[((size_t)l * CH + nn) * CH + c] * sc);
      if (c == 0) {
        const float* bs = (n < 192) ? bq : (n < 384) ? bk : bv;
        Bqkv[l * 576 + n] = bs[l * CH + nn] * sc;
      }
    } else if (i < n0 + n1) {
      int j = i - n0;
      Wob[j] = f2bf(wo[j]);
    } else if (i < n0 + n1 + n2) {
      int j = i - n0 - n1;           // dst [L][3][FCH][CH]
      int c = j % CH; int t1 = j / CH;
      int f = t1 % FCH; int t2 = t1 / FCH;
      int kk = t2 % 3; int l = t2 / 3;
      W1b[j] = f2bf(fw1[(((size_t)l * FCH + f) * CH + c) * 3 + kk]);
    } else {
      int j = i - n0 - n1 - n2;      // dst [L][3][CH][FCH]
      int c = j % FCH; int t1 = j / FCH;
      int f = t1 % CH; int t2 = t1 / CH;
      int kk = t2 % 3; int l = t2 / 3;
      W2b[j] = f2bf(fw2[(((size_t)l * CH + f) * FCH + c) * 3 + kk]);
    }
  }
}

// ---------- transpose in/out ----------
__global__ __launch_bounds__(256) void tin_kernel(const float* __restrict__ x,
    const float* __restrict__ mask, float* __restrict__ Xc, unsigned short* __restrict__ Xbf) {
  __shared__ float ls[32][33];
  int b = blockIdx.z; int c0 = blockIdx.y * 32, t0 = blockIdx.x * 32;
  int tx = threadIdx.x & 31, ty = threadIdx.x >> 5;
  #pragma unroll
  for (int j = 0; j < 4; ++j)
    ls[ty + j * 8][tx] = x[((size_t)b * CH + c0 + ty + j * 8) * TLEN + t0 + tx];
  __syncthreads();
  #pragma unroll
  for (int j = 0; j < 4; ++j) {
    int t = t0 + ty + j * 8;
    float v = ls[tx][ty + j * 8] * mask[b * TLEN + t];
    size_t o = ((size_t)b * TLEN + t) * CH + c0 + tx;
    Xc[o] = v; Xbf[o] = f2bf(v);
  }
}

__global__ __launch_bounds__(256) void tout_kernel(const float* __restrict__ Xc,
    const float* __restrict__ mask, float* __restrict__ out) {
  __shared__ float ls[32][33];
  int b = blockIdx.z; int c0 = blockIdx.y * 32, t0 = blockIdx.x * 32;
  int tx = threadIdx.x & 31, ty = threadIdx.x >> 5;
  #pragma unroll
  for (int j = 0; j < 4; ++j)
    ls[ty + j * 8][tx] = Xc[((size_t)b * TLEN + t0 + ty + j * 8) * CH + c0 + tx];
  __syncthreads();
  #pragma unroll
  for (int j = 0; j < 4; ++j)
    out[((size_t)b * CH + c0 + ty + j * 8) * TLEN + t0 + tx] =
        ls[tx][ty + j * 8] * mask[b * TLEN + t0 + tx];
}

// ---------- generic MFMA GEMM, BK=64, M-tile = MFR*32, reg-prefetch pipelined ----------
// OUTMODE: 0=bf16 [B][T][N], 2=f32 [B][T][N] (+ks*NBCT), 3=QKV fused epilogue
template<int OUTMODE, int NSHIFT, int RELU, int KSPLIT, int MFR>
__global__ __launch_bounds__(256) void gemm_tc(
    const unsigned short* __restrict__ A, const unsigned short* __restrict__ Bw,
    const float* __restrict__ bias, void* __restrict__ Y, int Cin, int N)
{
  constexpr int HALO = (NSHIFT == 3) ? 1 : 0;
  constexpr int AROWS = MFR * 32 + 2 * HALO;
  constexpr int ACH = (AROWS * 8 + 255) / 256;       // per-thread A-stage chunks
  constexpr int BCH = (NSHIFT * 64 * 8) / 256;       // per-thread B-stage chunks (exact)
  __shared__ __align__(16) unsigned short As[AROWS][72];
  __shared__ __align__(16) unsigned short Bs[NSHIFT][64][72];
  int zz = blockIdx.z;
  int b = zz / KSPLIT, ks = zz % KSPLIT;
  int t0 = blockIdx.x * (MFR * 32), n0 = blockIdx.y * 64;
  int tid = threadIdx.x;
  int w = tid >> 6, lane = tid & 63;
  int wr = w >> 1, wc = w & 1;
  int lr = lane & 15, lg = lane >> 4;
  const unsigned short* Ab = A + (size_t)b * TLEN * Cin;
  int klen = Cin / KSPLIT, k0 = ks * klen;

  // loop-invariant staging indices
  int ar[ACH], ac8[ACH]; bool aok[ACH], ain[ACH];
  #pragma unroll
  for (int j = 0; j < ACH; ++j) {
    int f = tid + j * 256;
    ar[j] = f >> 3; ac8[j] = (f & 7) * 8;
    aok[j] = (f < AROWS * 8);
    int tg = t0 - HALO + ar[j];
    ain[j] = aok[j] && (!HALO || (tg >= 0 && tg < TLEN));
  }
  int brr[BCH], bkk[BCH], bc8[BCH];
  #pragma unroll
  for (int j = 0; j < BCH; ++j) {
    int f = tid + j * 256;
    bkk[j] = f >> 9; brr[j] = (f >> 3) & 63; bc8[j] = (f & 7) * 8;
  }

  u16x8 areg[ACH], breg[BCH];
  f32x4 acc[MFR][2] = {};

  // prologue: load first K-step into registers
  #pragma unroll
  for (int j = 0; j < ACH; ++j) {
    u16x8 v = {};
    if (ain[j]) v = *(const u16x8*)&Ab[(size_t)(t0 - HALO + ar[j]) * Cin + k0 + ac8[j]];
    areg[j] = v;
  }
  #pragma unroll
  for (int j = 0; j < BCH; ++j)
    breg[j] = *(const u16x8*)&Bw[((size_t)bkk[j] * N + n0 + brr[j]) * Cin + k0 + bc8[j]];

  for (int kc = k0; kc < k0 + klen; kc += 64) {
    __syncthreads();     // previous MFMA phase done reading LDS
    #pragma unroll
    for (int j = 0; j < ACH; ++j)
      if (aok[j]) *(u16x8*)&As[ar[j]][ac8[j]] = areg[j];
    #pragma unroll
    for (int j = 0; j < BCH; ++j)
      *(u16x8*)&Bs[bkk[j]][brr[j]][bc8[j]] = breg[j];
    if (kc + 64 < k0 + klen) {   // issue next K-step's loads; latency hides under MFMA
      int kn = kc + 64;
      #pragma unroll
      for (int j = 0; j < ACH; ++j) {
        u16x8 v = {};
        if (ain[j]) v = *(const u16x8*)&Ab[(size_t)(t0 - HALO + ar[j]) * Cin + kn + ac8[j]];
        areg[j] = v;
      }
      #pragma unroll
      for (int j = 0; j < BCH; ++j)
        breg[j] = *(const u16x8*)&Bw[((size_t)bkk[j] * N + n0 + brr[j]) * Cin + kn + bc8[j]];
    }
    __syncthreads();
    #pragma unroll
    for (int kk = 0; kk < NSHIFT; ++kk) {
      #pragma unroll
      for (int k2 = 0; k2 < 2; ++k2) {
        bf16x8 b0 = *(const bf16x8*)&Bs[kk][wc * 32 + lr][k2 * 32 + lg * 8];
        bf16x8 b1 = *(const bf16x8*)&Bs[kk][wc * 32 + 16 + lr][k2 * 32 + lg * 8];
        #pragma unroll
        for (int i = 0; i < MFR; ++i) {
          bf16x8 a = *(const bf16x8*)&As[wr * MFR * 16 + i * 16 + lr + kk][k2 * 32 + lg * 8];
          acc[i][0] = __builtin_amdgcn_mfma_f32_16x16x32_bf16(a, b0, acc[i][0], 0, 0, 0);
          acc[i][1] = __builtin_amdgcn_mfma_f32_16x16x32_bf16(a, b1, acc[i][1], 0, 0, 0);
        }
      }
    }
  }
  #pragma unroll
  for (int i = 0; i < MFR; ++i) {
    #pragma unroll
    for (int j = 0; j < 2; ++j) {
      int n = n0 + wc * 32 + j * 16 + lr;
      float bb = (ks == 0) ? bias[n] : 0.f;
      float vals[4];
      #pragma unroll
      for (int r = 0; r < 4; ++r) {
        float v = acc[i][j][r] + bb;
        if (RELU) v = fmaxf(v, 0.f);
        vals[r] = v;
      }
      int trow = t0 + wr * MFR * 16 + i * 16 + lg * 4;
      if (OUTMODE == 0) {
        unsigned short* Yp = (unsigned short*)Y + ((size_t)b * TLEN + trow) * N + n;
        #pragma unroll
        for (int r = 0; r < 4; ++r) Yp[(size_t)r * N] = f2bf(vals[r]);
      } else if (OUTMODE == 2) {
        float* Yp = (float*)Y + (size_t)ks * NBCT + ((size_t)b * TLEN + trow) * N + n;
        #pragma unroll
        for (int r = 0; r < 4; ++r) Yp[(size_t)r * N] = vals[r];
      } else {  // QKV fused: n tile uniform within one of Q/K/V
        unsigned short* base = (unsigned short*)Y;
        if (n0 < 192) {
          unsigned short* Yp = base + ((size_t)b * TLEN + trow) * CH + n;
          #pragma unroll
          for (int r = 0; r < 4; ++r) Yp[(size_t)r * CH] = f2bf(vals[r]);
        } else if (n0 < 384) {
          unsigned short* Yp = base + (size_t)NBCT + ((size_t)b * TLEN + trow) * CH + (n - 192);
          #pragma unroll
          for (int r = 0; r < 4; ++r) Yp[(size_t)r * CH] = f2bf(vals[r]);
        } else {
          ushort4 pk;
          pk.x = f2bf(vals[0]); pk.y = f2bf(vals[1]); pk.z = f2bf(vals[2]); pk.w = f2bf(vals[3]);
          *(ushort4*)(base + 2 * (size_t)NBCT + ((size_t)b * CH + (n - 384)) * TLEN + trow) = pk;
        }
      }
    }
  }
}

// ---------- fused residual + channel LayerNorm ----------
template<int NY>
__global__ __launch_bounds__(256) void ln_cl_kernel(
    const float* __restrict__ res, const float* __restrict__ y0,
    const float* __restrict__ y1, const float* __restrict__ g,
    const float* __restrict__ bt, float* __restrict__ Xc, unsigned short* __restrict__ Xbf)
{
  int row = blockIdx.x * 4 + (threadIdx.x >> 6);
  int lane = threadIdx.x & 63;
  const float* r = res + (size_t)row * CH;
  const float* ya = y0 + (size_t)row * CH;
  const float* yb = (NY == 2) ? y1 + (size_t)row * CH : nullptr;
  float v[3]; float s = 0.f, s2 = 0.f;
  #pragma unroll
  for (int j = 0; j < 3; ++j) {
    float t = r[lane + 64 * j] + ya[lane + 64 * j];
    if (NY == 2) t += yb[lane + 64 * j];
    v[j] = t; s += t; s2 += t * t;
  }
  #pragma unroll
  for (int m = 1; m <= 32; m <<= 1) {
    s += __shfl_xor(s, m, 64);
    s2 += __shfl_xor(s2, m, 64);
  }
  float mean = s * (1.f / CH);
  float var = s2 * (1.f / CH) - mean * mean;
  float rs = rsqrtf(var + EPSV);
  #pragma unroll
  for (int j = 0; j < 3; ++j) {
    int c = lane + 64 * j;
    float o = g[c] * (v[j] - mean) * rs + bt[c];
    size_t idx = (size_t)row * CH + c;
    Xc[idx] = o; Xbf[idx] = f2bf(o);
  }
}

// ---------- flash attention partial (s-chunked, swapped-QK, base-2, dbuf) ----------
__global__ __launch_bounds__(256, 4) void flash_part(
    const unsigned short* __restrict__ Qg, const unsigned short* __restrict__ Kg,
    const unsigned short* __restrict__ Vg, const float* __restrict__ relk,
    float* __restrict__ Opart, float* __restrict__ mG, float* __restrict__ lG,
    float* __restrict__ bandG)
{
  __shared__ __align__(16) unsigned short KsB[64 * 104];
  __shared__ __align__(16) unsigned short QV[96 * 72];   // Qs[64][104] then Vs[96][72]
  __shared__ __align__(16) unsigned short Ps[64][72];
  __shared__ float qrk[64][9];
  int bh = blockIdx.y; int b = bh >> 1, h = bh & 1;
  int t0 = blockIdx.x * 64;
  int c0 = blockIdx.z * CHUNK;
  int tid = threadIdx.x; int w = tid >> 6, lane = tid & 63;
  int lr = lane & 15, lg = lane >> 4;
  int q = w * 16 + lr;                 // this thread's softmax-state query row
  const unsigned short* Qb = Qg + (size_t)b * TLEN * CH + h * DKH;
  const unsigned short* Kb = Kg + (size_t)b * TLEN * CH + h * DKH;
  const unsigned short* Vb = Vg + ((size_t)b * CH + h * DKH) * TLEN;
  unsigned short (*Qs)[104] = (unsigned short(*)[104])QV;
  unsigned short (*Vs)[72] = (unsigned short(*)[72])QV;
  unsigned short (*Ks)[104] = (unsigned short(*)[104])KsB;

  // staging index precompute (3 u16x8 per thread for K and for V)
  int kr[3], kc8[3], vr[3], vc8[3];
  #pragma unroll
  for (int j = 0; j < 3; ++j) {
    int f = tid + j * 256;
    kr[j] = f / 12; kc8[j] = (f % 12) * 8;
    vr[j] = f >> 3; vc8[j] = (f & 7) * 8;
  }

  for (int f = tid; f < 64 * 12; f += 256) {
    int r = f / 12, c8 = (f % 12) * 8;
    *(u16x8*)&Qs[r][c8] = *(const u16x8*)&Qb[(size_t)(t0 + r) * CH + c8];
  }
  __syncthreads();
  bool overlap = (t0 + 64 + WIN > c0) && (t0 - WIN < c0 + CHUNK);
  if (overlap) {
    for (int f = tid; f < 576; f += 256) {
      int r = f / 9, dd = f - (f / 9) * 9;
      float s = 0.f;
      #pragma unroll 8
      for (int d = 0; d < DKH; ++d) s += bf2f(Qs[r][d]) * relk[dd * DKH + d];
      qrk[r][dd] = s;    // already in base-2 domain (Q pre-scaled by log2e)
    }
  }
  bf16x8 qf[3];
  #pragma unroll
  for (int kc = 0; kc < 3; ++kc) qf[kc] = *(const bf16x8*)&Qs[q][kc * 32 + lg * 8];
  float mrow = -1e30f, lrow = 0.f;
  f32x4 oacc[6] = {};

  // prologue: prefetch tile 0 into registers
  u16x8 kreg[3], vreg[3];
  #pragma unroll
  for (int j = 0; j < 3; ++j)
    kreg[j] = *(const u16x8*)&Kb[(size_t)(c0 + kr[j]) * CH + kc8[j]];
  #pragma unroll
  for (int j = 0; j < 3; ++j)
    vreg[j] = *(const u16x8*)&Vb[(size_t)vr[j] * TLEN + c0 + vc8[j]];

  for (int it = 0; it < CHUNK / 64; ++it) {
    int s0 = c0 + it * 64;
    __syncthreads();                      // prev compute (and Q use) done
    #pragma unroll
    for (int j = 0; j < 3; ++j) *(u16x8*)&Ks[kr[j]][kc8[j]] = kreg[j];
    #pragma unroll
    for (int j = 0; j < 3; ++j) *(u16x8*)&Vs[vr[j]][vc8[j]] = vreg[j];
    if (it + 1 < CHUNK / 64) {            // issue next tile's loads (hide under compute)
      int sn = s0 + 64;
      #pragma unroll
      for (int j = 0; j < 3; ++j)
        kreg[j] = *(const u16x8*)&Kb[(size_t)(sn + kr[j]) * CH + kc8[j]];
      #pragma unroll
      for (int j = 0; j < 3; ++j)
        vreg[j] = *(const u16x8*)&Vb[(size_t)vr[j] * TLEN + sn + vc8[j]];
    }
    __syncthreads();

    // S^T tile: sacc[ct][r] = S[s = ct*16+lg*4+r][q]
    f32x4 sacc[4] = {};
    __builtin_amdgcn_s_setprio(1);
    #pragma unroll
    for (int kc = 0; kc < 3; ++kc) {
      #pragma unroll
      for (int ct = 0; ct < 4; ++ct) {
        bf16x8 kfr = *(const bf16x8*)&Ks[ct * 16 + lr][kc * 32 + lg * 8];
        sacc[ct] = __builtin_amdgcn_mfma_f32_16x16x32_bf16(kfr, qf[kc], sacc[ct], 0, 0, 0);
      }
    }
    __builtin_amdgcn_s_setprio(0);
    // band bias (only on diagonal-overlapping tiles; block-uniform predicate)
    if (s0 + 64 + WIN > t0 && s0 < t0 + 64 + WIN) {
      #pragma unroll
      for (int ct = 0; ct < 4; ++ct)
        #pragma unroll
        for (int r = 0; r < 4; ++r) {
          int dlt = (s0 + ct * 16 + lg * 4 + r) - (t0 + q);
          if (dlt >= -WIN && dlt <= WIN) {
            float v = sacc[ct][r] + qrk[q][dlt + WIN];
            sacc[ct][r] = v;
            bandG[((size_t)bh * TLEN + t0 + q) * 9 + dlt + WIN] = v;  // logit, exactly-once
          }
        }
    }
    float cm[4];
    #pragma unroll
    for (int ct = 0; ct < 4; ++ct)
      cm[ct] = fmaxf(fmaxf(sacc[ct][0], sacc[ct][1]), fmaxf(sacc[ct][2], sacc[ct][3]));
    float tmax = fmaxf(fmaxf(cm[0], cm[1]), fmaxf(cm[2], cm[3]));
    tmax = fmaxf(tmax, __shfl_xor(tmax, 16, 64));
    tmax = fmaxf(tmax, __shfl_xor(tmax, 32, 64));
    // defer-rescale: skip alpha path if no q in this wave grew past mrow+8
    bool upd = !__all(tmax <= mrow + 8.f);
    float mnew = upd ? fmaxf(mrow, tmax) : mrow;
    float psum = 0.f;
    #pragma unroll
    for (int ct = 0; ct < 4; ++ct) {
      float p0 = exp2a(sacc[ct][0] - mnew), p1 = exp2a(sacc[ct][1] - mnew);
      float p2 = exp2a(sacc[ct][2] - mnew), p3 = exp2a(sacc[ct][3] - mnew);
      psum += (p0 + p1) + (p2 + p3);
      ushort4 pk;
      pk.x = f2bf(p0); pk.y = f2bf(p1); pk.z = f2bf(p2); pk.w = f2bf(p3);
      *(ushort4*)&Ps[q][ct * 16 + lg * 4] = pk;
    }
    psum += __shfl_xor(psum, 16, 64);
    psum += __shfl_xor(psum, 32, 64);
    if (upd) {
      float alpha = exp2a(mrow - mnew);      // alpha for q = w*16+lr
      lrow *= alpha;
      // oacc rows are q_out = w*16 + lg*4 + r -> need THOSE rows' alphas
      float alo[4];
      #pragma unroll
      for (int r = 0; r < 4; ++r) alo[r] = __shfl(alpha, lg * 4 + r, 64);
      #pragma unroll
      for (int dt = 0; dt < 6; ++dt)
        #pragma unroll
        for (int r = 0; r < 4; ++r) oacc[dt][r] *= alo[r];
      mrow = mnew;
    }
    lrow += psum;
    __builtin_amdgcn_s_setprio(1);
    #pragma unroll
    for (int ks = 0; ks < 2; ++ks) {
      bf16x8 pa = *(const bf16x8*)&Ps[q][ks * 32 + lg * 8];
      #pragma unroll
      for (int dt = 0; dt < 6; ++dt) {
        bf16x8 vf = *(const bf16x8*)&Vs[dt * 16 + lr][ks * 32 + lg * 8];
        oacc[dt] = __builtin_amdgcn_mfma_f32_16x16x32_bf16(pa, vf, oacc[dt], 0, 0, 0);
      }
    }
    __builtin_amdgcn_s_setprio(0);
  }

  size_t pbase = ((size_t)blockIdx.z * (BATCH * NH) + bh) * TLEN + t0;
  #pragma unroll
  for (int dt = 0; dt < 6; ++dt)
    #pragma unroll
    for (int r = 0; r < 4; ++r)
      Opart[(pbase + w * 16 + lg * 4 + r) * 96 + dt * 16 + lr] = oacc[dt][r];
  if (lg == 0) {
    mG[pbase + q] = mrow;
    lG[pbase + q] = lrow;
  }
}

// ---------- flash combine (base-2) ----------
__global__ __launch_bounds__(256) void flash_combine(
    const float* __restrict__ Opart, const float* __restrict__ mG,
    const float* __restrict__ lG, const float* __restrict__ bandG,
    const float* __restrict__ relv, unsigned short* __restrict__ AO)
{
  int sub = threadIdx.x >> 7;
  int d = threadIdx.x & 127;
  int row = blockIdx.x * 2 + sub;            // bh*T + t
  int bh = row >> 11, t = row & 2047;
  float mv[SCH], lv[SCH], m = -1e30f;
  #pragma unroll
  for (int c = 0; c < SCH; ++c) {
    mv[c] = mG[(size_t)c * BHT + row];
    lv[c] = lG[(size_t)c * BHT + row];
    m = fmaxf(m, mv[c]);
  }
  float L = 0.f, e[SCH];
  #pragma unroll
  for (int c = 0; c < SCH; ++c) { e[c] = exp2a(mv[c] - m); L += lv[c] * e[c]; }
  if (d < 96) {
    float acc = 0.f;
    #pragma unroll
    for (int c = 0; c < SCH; ++c)
      acc += Opart[((size_t)c * BHT + row) * 96 + d] * e[c];
    #pragma unroll
    for (int dd = 0; dd < 9; ++dd) {
      int s = t + dd - WIN;
      if (s >= 0 && s < TLEN)
        acc += exp2a(bandG[(size_t)row * 9 + dd] - m) * relv[dd * 96 + d];
    }
    int b = bh >> 1, h = bh & 1;
    AO[((size_t)b * TLEN + t) * CH + h * DKH + d] = f2bf(acc / L);
  }
}

extern "C" void kernel_launch(void* const* d_in, const int* in_sizes, int n_in,
                              void* d_out, int out_size, void* d_ws, size_t ws_size,
                              hipStream_t stream) {
  (void)in_sizes; (void)n_in; (void)out_size; (void)ws_size;
  const float* x    = (const float*)d_in[0];
  const float* mask = (const float*)d_in[1];
  const float* wq   = (const float*)d_in[2];
  const float* bq   = (const float*)d_in[3];
  const float* wk   = (const float*)d_in[4];
  const float* bk   = (const float*)d_in[5];
  const float* wv   = (const float*)d_in[6];
  const float* bv   = (const float*)d_in[7];
  const float* wo   = (const float*)d_in[8];
  const float* bo   = (const float*)d_in[9];
  const float* relk = (const float*)d_in[10];
  const float* relv = (const float*)d_in[11];
  const float* ln1g = (const float*)d_in[12];
  const float* ln1b = (const float*)d_in[13];
  const float* fw1  = (const float*)d_in[14];
  const float* fb1  = (const float*)d_in[15];
  const float* fw2  = (const float*)d_in[16];
  const float* fb2  = (const float*)d_in[17];
  const float* ln2g = (const float*)d_in[18];
  const float* ln2b = (const float*)d_in[19];

  char* p = (char*)d_ws;
  float* Xc = (float*)p;                      p += (size_t)NBCT * 4;
  unsigned short* Xbf  = (unsigned short*)p;  p += (size_t)NBCT * 2;
  unsigned short* Qbf  = (unsigned short*)p;  p += (size_t)NBCT * 2;  // K,V contiguous after Q
  unsigned short* Kbf  = (unsigned short*)p;  p += (size_t)NBCT * 2;
  unsigned short* Vbf  = (unsigned short*)p;  p += (size_t)NBCT * 2;
  unsigned short* AObf = (unsigned short*)p;  p += (size_t)NBCT * 2;
  char* R = p;                                p += (size_t)NBCT * 8 + (size_t)NBFT * 2;
  float* Yo  = (float*)R;                               // [B][T][C] f32 (ks=0)
  float* Opart = (float*)R;                             // overlays Yo|Yo2|Hbf
  unsigned short* Hbf = (unsigned short*)(R + (size_t)NBCT * 8);
  float* mG = (float*)p;                      p += (size_t)SCH * BHT * 4;
  float* lG = (float*)p;                      p += (size_t)SCH * BHT * 4;
  float* bandG = (float*)p;                   p += (size_t)BHT * 9 * 4;
  unsigned short* Wqkv = (unsigned short*)p;  p += (size_t)LNUM * 576 * CH * 2;
  float* Bqkv = (float*)p;                    p += (size_t)LNUM * 576 * 4;
  unsigned short* Wob  = (unsigned short*)p;  p += (size_t)LNUM * CH * CH * 2;
  unsigned short* W1b  = (unsigned short*)p;  p += (size_t)LNUM * 3 * FCH * CH * 2;
  unsigned short* W2b  = (unsigned short*)p;

  prep_all<<<2048, 256, 0, stream>>>(wq, wk, wv, bq, bk, bv, wo, fw1, fw2,
                                     Wqkv, Bqkv, Wob, W1b, W2b);
  tin_kernel<<<dim3(TLEN / 32, CH / 32, BATCH), 256, 0, stream>>>(x, mask, Xc, Xbf);

  for (int l = 0; l < LNUM; ++l) {
    gemm_tc<3, 1, 0, 1, 4><<<dim3(16, 9, 4), 256, 0, stream>>>(
        Xbf, Wqkv + (size_t)l * 576 * CH, Bqkv + l * 576, Qbf, CH, 576);
    flash_part<<<dim3(32, 8, SCH), 256, 0, stream>>>(
        Qbf, Kbf, Vbf, relk + (size_t)l * 9 * DKH, Opart, mG, lG, bandG);
    flash_combine<<<BHT / 2, 256, 0, stream>>>(
        Opart, mG, lG, bandG, relv + (size_t)l * 9 * DKH, AObf);
    gemm_tc<2, 1, 0, 1, 2><<<dim3(32, 3, 4), 256, 0, stream>>>(
        AObf, Wob + (size_t)l * CH * CH, bo + l * CH, Yo, CH, CH);
    ln_cl_kernel<1><<<BATCH * TLEN / 4, 256, 0, stream>>>(
        Xc, Yo, nullptr, ln1g + l * CH, ln1b + l * CH, Xc, Xbf);
    gemm_tc<0, 3, 1, 1, 4><<<dim3(16, 12, 4), 256, 0, stream>>>(
        Xbf, W1b + (size_t)l * 3 * FCH * CH, fb1 + l * FCH, Hbf, CH, FCH);
    gemm_tc<2, 3, 0, 2, 2><<<dim3(32, 3, 8), 256, 0, stream>>>(
        Hbf, W2b + (size_t)l * 3 * CH * FCH, fb2 + l * CH, Yo, FCH, CH);
    ln_cl_kernel<2><<<BATCH * TLEN / 4, 256, 0, stream>>>(
        Xc, Yo, Yo + NBCT, ln2g + l * CH, ln2b + l * CH, Xc, Xbf);
  }
  tout_kernel<<<dim3(TLEN / 32, CH / 32, BATCH), 256, 0, stream>>>(Xc, mask, (float*)d_out);
}